// Round 5
// baseline (512.264 us; speedup 1.0000x reference)
//
#include <hip/hip_runtime.h>
#include <cstdint>
#include <cstddef>

using u16 = unsigned short;
using u32 = unsigned int;

typedef __bf16 bf16x8 __attribute__((ext_vector_type(8)));
typedef float  f32x4  __attribute__((ext_vector_type(4)));

__device__ __forceinline__ float bf2f(u16 b) { union { u32 i; float f; } v; v.i = ((u32)b) << 16; return v.f; }
__device__ __forceinline__ u16 f2bf(float f) { __bf16 b = (__bf16)f; return __builtin_bit_cast(u16, b); }
__device__ __forceinline__ float bflo(u32 u) { union { u32 i; float f; } v; v.i = u << 16; return v.f; }
__device__ __forceinline__ float bfhi(u32 u) { union { u32 i; float f; } v; v.i = u & 0xffff0000u; return v.f; }
__device__ __forceinline__ u32 pack2(float a, float b) { return (u32)f2bf(a) | ((u32)f2bf(b) << 16); }

__device__ __forceinline__ float loadx(const void* p, size_t i, int flag_bf16) {
    return flag_bf16 ? bf2f(((const u16*)p)[i]) : ((const float*)p)[i];
}
__device__ __forceinline__ void storex(void* p, size_t i, float v, int flag_bf16) {
    if (flag_bf16) ((u16*)p)[i] = f2bf(v);
    else           ((float*)p)[i] = v;
}

__device__ __forceinline__ bf16x8 load_afrag_ext(const void* A, size_t off, int flag) {
    if (flag) return *reinterpret_cast<const bf16x8*>((const u16*)A + off);
    const float* f = (const float*)A + off;
    float4 a = *reinterpret_cast<const float4*>(f);
    float4 b = *reinterpret_cast<const float4*>(f + 4);
    bf16x8 r;
    r[0] = (__bf16)a.x; r[1] = (__bf16)a.y; r[2] = (__bf16)a.z; r[3] = (__bf16)a.w;
    r[4] = (__bf16)b.x; r[5] = (__bf16)b.y; r[6] = (__bf16)b.z; r[7] = (__bf16)b.w;
    return r;
}

// ---------------- dtype detection ----------------
__global__ void k_detect(const u32* __restrict__ x, int* __restrict__ flag) {
    int lane = threadIdx.x;
    u32 u = x[lane];
    int e = (u >> 7) & 0xFF;
    int hit = (e >= 100 && e <= 145) ? 1 : 0;
    unsigned long long b = __ballot(hit);
    if (lane == 0) flag[0] = (__popcll(b) >= 32) ? 1 : 0;
}

// ---------------- weight conversion ----------------
struct ConvJob { const void* src; float* dst; int n; };
struct ConvJobs { ConvJob j[12]; };

__global__ void k_wconv(ConvJobs jobs, const int* __restrict__ flagp) {
    const int f = *flagp;
    const int stride = gridDim.x * blockDim.x;
    for (int s = 0; s < 12; ++s) {
        const ConvJob jb = jobs.j[s];
        for (int i = blockIdx.x * blockDim.x + threadIdx.x; i < jb.n; i += stride)
            jb.dst[i] = loadx(jb.src, i, f);
    }
}

struct TJob { const float* W; u16* WT; int K, NC; };
struct TJobs { TJob j[5]; };

__global__ void k_wtrans(TJobs jobs) {
    const int stride = gridDim.x * blockDim.x;
    for (int s = 0; s < 5; ++s) {
        const TJob jb = jobs.j[s];
        const int tot = jb.K * jb.NC;
        for (int i = blockIdx.x * blockDim.x + threadIdx.x; i < tot; i += stride) {
            int k = i / jb.NC, n = i - k * jb.NC;
            jb.WT[n * jb.K + k] = f2bf(jb.W[i]);
        }
    }
}

// ---------------- graph preprocessing: block-chunk radix binning ----------------
static const int CAPSH = 12;        // 4096 entries per (g,bucket) cell (avg fill ~2045)
static const int OVCAP = 65536;     // overflow list capacity (never hit for uniform input)

__global__ __launch_bounds__(256) void k_bin(const int* __restrict__ ei0, const int* __restrict__ ei1,
                                             int* __restrict__ cur, u32* __restrict__ stage,
                                             int2* __restrict__ ov, int* __restrict__ ocnt,
                                             int E, int NB, int nblk) {
    const int g = blockIdx.y;
    const int* ei = g ? ei1 : ei0;
    const int chunk = (E + nblk - 1) / nblk;
    const int e0 = blockIdx.x * chunk;
    const int e1 = (e0 + chunk < E) ? e0 + chunk : E;
    const int tid = threadIdx.x;
    __shared__ int h[512];
    __shared__ int lb[512];
    for (int i = tid; i < NB; i += 256) h[i] = 0;
    __syncthreads();
    for (int e = e0 + tid; e < e1; e += 256) {
        int d = __builtin_nontemporal_load(ei + E + e);
        atomicAdd(&h[d >> 7], 1);
    }
    __syncthreads();
    for (int b = tid; b < NB; b += 256) {
        int c = h[b];
        lb[b] = c ? atomicAdd(&cur[g * NB + b], c) : 0;
    }
    __syncthreads();
    for (int i = tid; i < NB; i += 256) h[i] = 0;
    __syncthreads();
    for (int e = e0 + tid; e < e1; e += 256) {
        int s = __builtin_nontemporal_load(ei + e);
        int d = ei[E + e];  // re-read: L2-resident from pass 1
        int b = d >> 7;
        int p = lb[b] + atomicAdd(&h[b], 1);
        if (p < (1 << CAPSH)) {
            stage[((size_t)(g * NB + b) << CAPSH) + p] = (u32)s | ((u32)(d & 127) << 16);
        } else {
            int oi = atomicAdd(ocnt, 1);
            if (oi < OVCAP) ov[oi] = make_int2(s, d | (g << 24));
        }
    }
}

__global__ __launch_bounds__(256) void k_bscan(const int* __restrict__ cur, const int2* __restrict__ ov,
                                               const int* __restrict__ ocnt, int* __restrict__ bbase,
                                               int* __restrict__ rowptr, int N, int E, int NB) {
    __shared__ int tot[2][512];
    const int tid = threadIdx.x;
    for (int g = 0; g < 2; ++g)
        for (int i = tid; i < 512; i += 256) {
            int s = 0;
            if (i < NB) {
                int cv = cur[g * NB + i];
                s = (cv < (1 << CAPSH)) ? cv : (1 << CAPSH);
            }
            tot[g][i] = s;
        }
    __syncthreads();
    int no = *ocnt; if (no > OVCAP) no = OVCAP;
    for (int i = tid; i < no; i += 256) {
        int y = ov[i].y;
        atomicAdd(&tot[y >> 24][(y & 0xFFFFFF) >> 7], 1);
    }
    __syncthreads();
    int o00 = tot[0][tid], o01 = tot[0][tid + 256];
    int o10 = tot[1][tid], o11 = tot[1][tid + 256];
    for (int off = 1; off < 512; off <<= 1) {
        int a0 = tot[0][tid]       + ((tid >= off)       ? tot[0][tid - off]       : 0);
        int a1 = tot[0][tid + 256] + ((tid + 256 >= off) ? tot[0][tid + 256 - off] : 0);
        int b0 = tot[1][tid]       + ((tid >= off)       ? tot[1][tid - off]       : 0);
        int b1 = tot[1][tid + 256] + ((tid + 256 >= off) ? tot[1][tid + 256 - off] : 0);
        __syncthreads();
        tot[0][tid] = a0; tot[0][tid + 256] = a1;
        tot[1][tid] = b0; tot[1][tid + 256] = b1;
        __syncthreads();
    }
    if (tid < NB)       { bbase[tid]            = tot[0][tid] - o00;       bbase[NB + tid]       = tot[1][tid] - o10; }
    if (tid + 256 < NB) { bbase[tid + 256]      = tot[0][tid + 256] - o01; bbase[NB + tid + 256] = tot[1][tid + 256] - o11; }
    if (tid == 0) {
        rowptr[N] = E;
        rowptr[(size_t)(N + 1) + N] = E;
    }
}

__global__ __launch_bounds__(256) void k_scatter(const int* __restrict__ cur, const u32* __restrict__ stage,
                                                 const int2* __restrict__ ov, const int* __restrict__ ocnt,
                                                 const int* __restrict__ bbase, int* __restrict__ rowptr,
                                                 float* __restrict__ dinv, int* __restrict__ csr,
                                                 int N, int E, int NB) {
    const int g = blockIdx.y, b = blockIdx.x, tid = threadIdx.x;
    const int lo = b << 7;
    int R = N - lo; if (R > 128) R = 128;
    __shared__ int hist[128], scn[128], curs[128];
    if (tid < 128) hist[tid] = 0;
    __syncthreads();
    int cv = cur[g * NB + b];
    const int n = (cv < (1 << CAPSH)) ? cv : (1 << CAPSH);
    const u32* sp = stage + ((size_t)(g * NB + b) << CAPSH);
    for (int i = tid; i < n; i += 256) atomicAdd(&hist[sp[i] >> 16], 1);
    int no = *ocnt; if (no > OVCAP) no = OVCAP;
    for (int i = tid; i < no; i += 256) {
        int y = ov[i].y;
        if ((y >> 24) != g) continue;
        int d = y & 0xFFFFFF;
        if (d >= lo && d < lo + 128) atomicAdd(&hist[d - lo], 1);
    }
    __syncthreads();
    int orig = (tid < 128) ? hist[tid] : 0;
    if (tid < 128) scn[tid] = orig;
    __syncthreads();
    for (int off = 1; off < 128; off <<= 1) {
        int v = 0;
        if (tid < 128) v = scn[tid] + ((tid >= off) ? scn[tid - off] : 0);
        __syncthreads();
        if (tid < 128) scn[tid] = v;
        __syncthreads();
    }
    const int base = bbase[g * NB + b];
    if (tid < R) {
        int ex = base + scn[tid] - orig;   // exclusive prefix
        rowptr[(size_t)g * (N + 1) + lo + tid] = ex;
        curs[tid] = ex;
        dinv[(size_t)g * N + lo + tid] = rsqrtf((float)(orig + 1));  // +1 self loop
    }
    __syncthreads();
    int* out = csr + (size_t)g * E;
    for (int i = tid; i < n; i += 256) {
        u32 v = sp[i];
        int pos = atomicAdd(&curs[v >> 16], 1);
        out[pos] = (int)(v & 0xFFFFu);
    }
    for (int i = tid; i < no; i += 256) {
        int y = ov[i].y;
        if ((y >> 24) != g) continue;
        int d = y & 0xFFFFFF;
        if (d >= lo && d < lo + 128) {
            int pos = atomicAdd(&curs[d - lo], 1);
            out[pos] = ov[i].x;
        }
    }
}

// ---------------- MFMA GEMM ----------------
// SCALE: multiply output row by dvp[g*M+row] (pre-scale by dinv[src]).
// ASPLIT/OSPLIT (0,16,32): channel-split layout [g][ch/S][node][S] for the
// XCD-partitioned aggregation (each XCD owns one (g, ch-slice) role).
template <int K, int NC, bool AEXT, bool BIAS, bool RELU, bool NORM, bool OEXT, bool SCALE,
          int ASPLIT, int OSPLIT>
__global__ __launch_bounds__(256) void k_mgemm(const void* __restrict__ A0, const void* __restrict__ A1,
                                               size_t astride, const u16* __restrict__ WT,
                                               const float* __restrict__ bias, void* __restrict__ outv,
                                               size_t out_off, size_t ostride, int M,
                                               const int* __restrict__ flagp,
                                               const float* __restrict__ dvp) {
    constexpr int NT = NC / 16;
    constexpr int KI = K / 32;
    const int flag = *flagp;
    const int g = blockIdx.y;
    const void* Av = (ASPLIT != 0) ? A0 : (g ? A1 : A0);
    const int lane = threadIdx.x & 63;
    const int wave = threadIdx.x >> 6;
    const int q = lane >> 4;
    const int c = lane & 15;
    const int m0 = blockIdx.x * 64 + wave * 16;
    int arow = m0 + c;
    if (arow > M - 1) arow = M - 1;
    const size_t abase = (size_t)g * astride + (size_t)arow * K;

    bf16x8 afr[KI];
#pragma unroll
    for (int ki = 0; ki < KI; ++ki) {
        size_t off;
        if constexpr (ASPLIT == 32) {
            off = ((size_t)(g * (K / 32) + ki)) * ((size_t)M * 32) + (size_t)arow * 32 + q * 8;
        } else if constexpr (ASPLIT == 16) {
            off = ((size_t)(g * (K / 16) + ki * 2 + (q >> 1))) * ((size_t)M * 16) + (size_t)arow * 16 + (q & 1) * 8;
        } else {
            off = abase + (size_t)ki * 32 + q * 8;
        }
        if (AEXT) afr[ki] = load_afrag_ext(Av, off, flag);
        else      afr[ki] = *reinterpret_cast<const bf16x8*>((const u16*)Av + off);
    }

    f32x4 acc[NT];
#pragma unroll
    for (int t = 0; t < NT; ++t) acc[t] = (f32x4){0.f, 0.f, 0.f, 0.f};

#pragma unroll
    for (int ki = 0; ki < KI; ++ki) {
#pragma unroll
        for (int t = 0; t < NT; ++t) {
            const u16* bptr = WT + (size_t)(t * 16 + c) * K + ki * 32 + q * 8;
            bf16x8 bfr = *reinterpret_cast<const bf16x8*>(bptr);
            acc[t] = __builtin_amdgcn_mfma_f32_16x16x32_bf16(afr[ki], bfr, acc[t], 0, 0, 0);
        }
    }

#pragma unroll
    for (int t = 0; t < NT; ++t) {
        float bv = BIAS ? bias[t * 16 + c] : 0.f;
#pragma unroll
        for (int r = 0; r < 4; ++r) {
            float v = acc[t][r] + bv;
            if (RELU) v = fmaxf(v, 0.f);
            acc[t][r] = v;
        }
    }

    if constexpr (NORM) {
        float ss[4] = {0.f, 0.f, 0.f, 0.f};
#pragma unroll
        for (int t = 0; t < NT; ++t)
#pragma unroll
            for (int r = 0; r < 4; ++r) ss[r] += acc[t][r] * acc[t][r];
#pragma unroll
        for (int r = 0; r < 4; ++r) {
#pragma unroll
            for (int m = 1; m < 16; m <<= 1) ss[r] += __shfl_xor(ss[r], m, 64);
            float s = 1.f / fmaxf(sqrtf(ss[r]), 1e-12f);
#pragma unroll
            for (int t = 0; t < NT; ++t) acc[t][r] *= s;
        }
    }

    const size_t obase = out_off + (size_t)g * ostride;
#pragma unroll
    for (int r = 0; r < 4; ++r) {
        const int grow = m0 + q * 4 + r;
        if (grow < M) {
            float sc = 1.f;
            if constexpr (SCALE) sc = dvp[(size_t)g * M + grow];
#pragma unroll
            for (int t = 0; t < NT; ++t) {
                float v = SCALE ? acc[t][r] * sc : acc[t][r];
                const int ch = t * 16 + c;
                if constexpr (OSPLIT == 32) {
                    size_t oi = ((size_t)(g * (NC / 32) + (ch >> 5))) * ((size_t)M * 32) + (size_t)grow * 32 + (ch & 31);
                    ((u16*)outv)[oi] = f2bf(v);
                } else if constexpr (OSPLIT == 16) {
                    size_t oi = ((size_t)(g * (NC / 16) + (ch >> 4))) * ((size_t)M * 16) + (size_t)grow * 16 + (ch & 15);
                    ((u16*)outv)[oi] = f2bf(v);
                } else {
                    size_t oi = obase + (size_t)grow * NC + ch;
                    if (OEXT) storex(outv, oi, v, flag);
                    else      ((u16*)outv)[oi] = f2bf(v);
                }
            }
        }
    }
}

// ---------------- GCN aggregation, XCD channel-partitioned ----------------
// Role r = blockIdx.x & 7 (round-robin -> XCD r): g = r>>2, q = r&3.
// Role (g,q) gathers only a 64B channel-slice of H for ALL edges of graph g:
// per-XCD working set 3.2MB fits the 4MB XCD L2 -> fetch ~= compulsory.
// 4 edges per gather instruction (lane groups of 16, u32 = 2ch/lane) keeps
// channel-throughput per VALU inst identical to the unsplit kernel.
__global__ __launch_bounds__(256) void k_agg128(const u32* __restrict__ H, const int* __restrict__ rowptr,
                                                const int* __restrict__ csr, const float* __restrict__ dinv,
                                                const float* __restrict__ bias, u32* __restrict__ out,
                                                int N, int E) {
    const int bid = blockIdx.x;
    const int g = (bid >> 2) & 1;
    const int q = bid & 3;
    const int nb = bid >> 3;
    const int lane = threadIdx.x & 63;
    const int wv = threadIdx.x >> 6;
    const int grp = lane >> 4;
    const int w = lane & 15;
    const u32* h = H + (size_t)(g * 4 + q) * N * 16;
    const int* rp = rowptr + (size_t)g * (N + 1);
    const int* cs = csr + (size_t)g * E;
    u32* o = out + (size_t)(g * 4 + q) * N * 16;
#pragma unroll
    for (int i = 0; i < 2; ++i) {
        const int node = nb * 8 + wv * 2 + i;
        if (node >= N) return;
        int e = rp[node];
        const int end = rp[node + 1];
        u32 su = (grp == 0) ? h[(size_t)node * 16 + w] : 0u;
        float a0 = bflo(su), a1 = bfhi(su);
        while (e < end) {
            int cnt = end - e; if (cnt > 64) cnt = 64;
            int my = (lane < cnt) ? cs[e + lane] : 0;
            int j = 0;
            for (; j + 16 <= cnt; j += 16) {
                int s0 = __shfl(my, j + grp, 64);
                int s1 = __shfl(my, j + 4 + grp, 64);
                int s2 = __shfl(my, j + 8 + grp, 64);
                int s3 = __shfl(my, j + 12 + grp, 64);
                u32 h0 = h[(size_t)s0 * 16 + w];
                u32 h1 = h[(size_t)s1 * 16 + w];
                u32 h2 = h[(size_t)s2 * 16 + w];
                u32 h3 = h[(size_t)s3 * 16 + w];
                a0 += bflo(h0); a1 += bfhi(h0);
                a0 += bflo(h1); a1 += bfhi(h1);
                a0 += bflo(h2); a1 += bfhi(h2);
                a0 += bflo(h3); a1 += bfhi(h3);
            }
            for (; j < cnt; j += 4) {
                int idx = j + grp;
                int src = __shfl(my, idx < cnt ? idx : 0, 64);
                if (idx < cnt) {
                    u32 hv = h[(size_t)src * 16 + w];
                    a0 += bflo(hv); a1 += bfhi(hv);
                }
            }
            e += cnt;
        }
        a0 += __shfl_xor(a0, 16, 64); a0 += __shfl_xor(a0, 32, 64);
        a1 += __shfl_xor(a1, 16, 64); a1 += __shfl_xor(a1, 32, 64);
        if (grp == 0) {
            float dn = dinv[(size_t)g * N + node];
            float b0 = bias[q * 32 + 2 * w];
            float b1 = bias[q * 32 + 2 * w + 1];
            float r0 = fmaxf(a0 * dn + b0, 0.f);
            float r1 = fmaxf(a1 * dn + b1, 0.f);
            o[(size_t)node * 16 + w] = pack2(r0, r1);
        }
    }
}

__global__ __launch_bounds__(256) void k_agg64(const u32* __restrict__ H, const int* __restrict__ rowptr,
                                               const int* __restrict__ csr, const float* __restrict__ dinv,
                                               const float* __restrict__ bias, u32* __restrict__ out,
                                               int N, int E) {
    const int bid = blockIdx.x;
    const int g = (bid >> 2) & 1;
    const int q = bid & 3;
    const int nb = bid >> 3;
    const int lane = threadIdx.x & 63;
    const int wv = threadIdx.x >> 6;
    const int grp = lane >> 3;
    const int w = lane & 7;
    const u32* h = H + (size_t)(g * 4 + q) * N * 8;
    const int* rp = rowptr + (size_t)g * (N + 1);
    const int* cs = csr + (size_t)g * E;
    u32* o = out + (size_t)(g * 4 + q) * N * 8;
#pragma unroll
    for (int i = 0; i < 2; ++i) {
        const int node = nb * 8 + wv * 2 + i;
        if (node >= N) return;
        int e = rp[node];
        const int end = rp[node + 1];
        u32 su = (grp == 0) ? h[(size_t)node * 8 + w] : 0u;
        float a0 = bflo(su), a1 = bfhi(su);
        while (e < end) {
            int cnt = end - e; if (cnt > 64) cnt = 64;
            int my = (lane < cnt) ? cs[e + lane] : 0;
            int j = 0;
            for (; j + 32 <= cnt; j += 32) {
                int s0 = __shfl(my, j + grp, 64);
                int s1 = __shfl(my, j + 8 + grp, 64);
                int s2 = __shfl(my, j + 16 + grp, 64);
                int s3 = __shfl(my, j + 24 + grp, 64);
                u32 h0 = h[(size_t)s0 * 8 + w];
                u32 h1 = h[(size_t)s1 * 8 + w];
                u32 h2 = h[(size_t)s2 * 8 + w];
                u32 h3 = h[(size_t)s3 * 8 + w];
                a0 += bflo(h0); a1 += bfhi(h0);
                a0 += bflo(h1); a1 += bfhi(h1);
                a0 += bflo(h2); a1 += bfhi(h2);
                a0 += bflo(h3); a1 += bfhi(h3);
            }
            for (; j < cnt; j += 8) {
                int idx = j + grp;
                int src = __shfl(my, idx < cnt ? idx : 0, 64);
                if (idx < cnt) {
                    u32 hv = h[(size_t)src * 8 + w];
                    a0 += bflo(hv); a1 += bfhi(hv);
                }
            }
            e += cnt;
        }
        a0 += __shfl_xor(a0, 8, 64); a0 += __shfl_xor(a0, 16, 64); a0 += __shfl_xor(a0, 32, 64);
        a1 += __shfl_xor(a1, 8, 64); a1 += __shfl_xor(a1, 16, 64); a1 += __shfl_xor(a1, 32, 64);
        if (grp == 0) {
            float dn = dinv[(size_t)g * N + node];
            float b0 = bias[q * 16 + 2 * w];
            float b1 = bias[q * 16 + 2 * w + 1];
            float r0 = fmaxf(a0 * dn + b0, 0.f);
            float r1 = fmaxf(a1 * dn + b1, 0.f);
            o[(size_t)node * 8 + w] = pack2(r0, r1);
        }
    }
}

// ---------------- cluster head ----------------
__global__ __launch_bounds__(256) void k_clus(const u16* __restrict__ v, const float* __restrict__ Wc2,
                                              const float* __restrict__ bc2, void* __restrict__ outv,
                                              size_t out_off, size_t ostride, int N,
                                              const int* __restrict__ flagp) {
    const int g = blockIdx.y;
    const int node = blockIdx.x * 4 + (threadIdx.x >> 6);
    if (node >= N) return;
    const int flag = *flagp;
    const int lane = threadIdx.x & 63;
    float ul = bf2f(v[((size_t)g * N + node) * 64 + lane]);
    float a0 = ul * Wc2[lane * 3 + 0];
    float a1 = ul * Wc2[lane * 3 + 1];
    float a2 = ul * Wc2[lane * 3 + 2];
#pragma unroll
    for (int m = 1; m < 64; m <<= 1) {
        a0 += __shfl_xor(a0, m, 64);
        a1 += __shfl_xor(a1, m, 64);
        a2 += __shfl_xor(a2, m, 64);
    }
    a0 += bc2[0]; a1 += bc2[1]; a2 += bc2[2];
    float mx = fmaxf(a0, fmaxf(a1, a2));
    float e0 = expf(a0 - mx), e1 = expf(a1 - mx), e2 = expf(a2 - mx);
    float inv = 1.f / (e0 + e1 + e2);
    if (lane < 3) {
        float r = (lane == 0) ? e0 : ((lane == 1) ? e1 : e2);
        storex(outv, out_off + (size_t)g * ostride + (size_t)node * 3 + lane, r * inv, flag);
    }
}

// ---------------- launcher ----------------
extern "C" void kernel_launch(void* const* d_in, const int* in_sizes, int n_in,
                              void* d_out, int out_size, void* d_ws, size_t ws_size,
                              hipStream_t stream) {
    const int N = in_sizes[0] / 128;   // 50000
    const int E = in_sizes[1] / 2;     // 800000
    const int* ei0 = (const int*)d_in[1];
    const int* ei1 = (const int*)d_in[3];
    const int NB = (N + 127) >> 7;     // 391 buckets of 128 nodes

    size_t off = 0;
    auto alloc = [&](size_t bytes) -> void* {
        void* p = (char*)d_ws + off;
        off += (bytes + 255) & ~(size_t)255;
        return p;
    };
    int* flag = (int*)alloc(256);
    const int wcnt[12] = {128 * 128, 128, 128 * 64, 64, 64 * 64, 64, 64 * 128, 128, 64 * 64, 64, 64 * 3, 3};
    float* wf[12];
    for (int i = 0; i < 12; ++i) wf[i] = (float*)alloc((size_t)wcnt[i] * 4);
    float* b1f = wf[1]; float* b2f = wf[3]; float* bp1f = wf[5]; float* bp2f = wf[7];
    float* bc1f = wf[9]; float* Wc2f = wf[10]; float* bc2f = wf[11];
    u16* W1T  = (u16*)alloc(128 * 128 * 2);
    u16* W2T  = (u16*)alloc(64 * 128 * 2);
    u16* Wp1T = (u16*)alloc(64 * 64 * 2);
    u16* Wp2T = (u16*)alloc(128 * 64 * 2);
    u16* Wc1T = (u16*)alloc(64 * 64 * 2);

    const int ncell = 2 * NB;
    int* cur    = (int*)alloc((size_t)(ncell + 1) * 4);   // +1: overflow count
    int* ocnt   = cur + ncell;
    int2* ov    = (int2*)alloc((size_t)OVCAP * 8);
    u32* stage  = (u32*)alloc(((size_t)ncell << CAPSH) * 4);
    int* bbase  = (int*)alloc((size_t)2 * NB * 4);
    int* rowptr = (int*)alloc((size_t)2 * (N + 1) * 4);
    float* dinv = (float*)alloc((size_t)2 * N * 4);
    int* csr    = (int*)alloc((size_t)2 * E * 4);
    u16* A1 = (u16*)alloc((size_t)2 * N * 128 * 2);   // layer-1 H, split32 layout
    u16* H2 = A1;                                     // layer-2 H, split16 layout
    u16* Qb = (u16*)alloc((size_t)2 * N * 128 * 2);   // agg1 out, split32 layout
    u16* U  = Qb;                                     // head intermediate, standard
    u16* Z  = (u16*)alloc((size_t)2 * N * 64 * 2);    // agg2 out, split16 layout
    (void)ws_size; (void)n_in; (void)out_size;

    k_detect<<<1, 64, 0, stream>>>((const u32*)d_in[0], flag);
    ConvJobs jobs;
    for (int i = 0; i < 12; ++i) jobs.j[i] = ConvJob{d_in[4 + i], wf[i], wcnt[i]};
    k_wconv<<<64, 256, 0, stream>>>(jobs, flag);
    TJobs tj;
    tj.j[0] = TJob{wf[0], W1T, 128, 128};
    tj.j[1] = TJob{wf[2], W2T, 128, 64};
    tj.j[2] = TJob{wf[4], Wp1T, 64, 64};
    tj.j[3] = TJob{wf[6], Wp2T, 64, 128};
    tj.j[4] = TJob{wf[8], Wc1T, 64, 64};
    k_wtrans<<<40, 256, 0, stream>>>(tj);

    hipMemsetAsync(cur, 0, (size_t)(ncell + 1) * 4, stream);
    const int NBLK = 128;   // per-graph blocks: chunk ~6250 edges -> runs of ~16 (1 line)
    k_bin<<<dim3(NBLK, 2), 256, 0, stream>>>(ei0, ei1, cur, stage, ov, ocnt, E, NB, NBLK);
    k_bscan<<<1, 256, 0, stream>>>(cur, ov, ocnt, bbase, rowptr, N, E, NB);
    k_scatter<<<dim3(NB, 2), 256, 0, stream>>>(cur, stage, ov, ocnt, bbase, rowptr, dinv, csr, N, E, NB);

    const dim3 gM((N + 63) / 64, 2);
    const dim3 gAg(8 * ((N + 7) / 8));   // flat: role = bid&7 -> (g,q) on one XCD
    const dim3 gA((N + 3) / 4, 2);

    // layer 1 (output pre-scaled by dinv[row], split32 layout)
    k_mgemm<128, 128, true, false, false, false, false, true, 0, 32><<<gM, 256, 0, stream>>>(
        d_in[0], d_in[2], 0, W1T, nullptr, A1, 0, (size_t)N * 128, N, flag, dinv);
    k_agg128<<<gAg, 256, 0, stream>>>((const u32*)A1, rowptr, csr, dinv, b1f, (u32*)Qb, N, E);
    // layer 2 (reads split32 Qb, writes split16 H2, pre-scaled by dinv[row])
    k_mgemm<128, 64, false, false, false, false, false, true, 32, 16><<<gM, 256, 0, stream>>>(
        Qb, Qb, 0, W2T, nullptr, H2, 0, (size_t)N * 64, N, flag, dinv);
    k_agg64<<<gAg, 256, 0, stream>>>((const u32*)H2, rowptr, csr, dinv, b2f, (u32*)Z, N, E);

    // instance head (reads split16 Z)
    k_mgemm<64, 64, false, true, true, false, false, false, 16, 0><<<gM, 256, 0, stream>>>(
        Z, Z, 0, Wp1T, bp1f, U, 0, (size_t)N * 64, N, flag, nullptr);
    k_mgemm<64, 128, false, true, false, true, true, false, 0, 0><<<gM, 256, 0, stream>>>(
        U, U, (size_t)N * 64, Wp2T, bp2f, d_out, 0, (size_t)N * 128, N, flag, nullptr);
    // cluster head (reads split16 Z)
    k_mgemm<64, 64, false, true, true, false, false, false, 16, 0><<<gM, 256, 0, stream>>>(
        Z, Z, 0, Wc1T, bc1f, U, 0, (size_t)N * 64, N, flag, nullptr);
    k_clus<<<gA, 256, 0, stream>>>(U, Wc2f, bc2f, d_out,
                                   (size_t)2 * N * 128, (size_t)N * 3, N, flag);
}

// Round 6
// 413.219 us; speedup vs baseline: 1.2397x; 1.2397x over previous
//
#include <hip/hip_runtime.h>
#include <cstdint>
#include <cstddef>

using u16 = unsigned short;
using u32 = unsigned int;

typedef __bf16 bf16x8 __attribute__((ext_vector_type(8)));
typedef float  f32x4  __attribute__((ext_vector_type(4)));

__device__ __forceinline__ float bf2f(u16 b) { union { u32 i; float f; } v; v.i = ((u32)b) << 16; return v.f; }
__device__ __forceinline__ u16 f2bf(float f) { __bf16 b = (__bf16)f; return __builtin_bit_cast(u16, b); }
__device__ __forceinline__ float bflo(u32 u) { union { u32 i; float f; } v; v.i = u << 16; return v.f; }
__device__ __forceinline__ float bfhi(u32 u) { union { u32 i; float f; } v; v.i = u & 0xffff0000u; return v.f; }
__device__ __forceinline__ u32 pack2(float a, float b) { return (u32)f2bf(a) | ((u32)f2bf(b) << 16); }

__device__ __forceinline__ float loadx(const void* p, size_t i, int flag_bf16) {
    return flag_bf16 ? bf2f(((const u16*)p)[i]) : ((const float*)p)[i];
}
__device__ __forceinline__ void storex(void* p, size_t i, float v, int flag_bf16) {
    if (flag_bf16) ((u16*)p)[i] = f2bf(v);
    else           ((float*)p)[i] = v;
}

__device__ __forceinline__ bf16x8 load_afrag_ext(const void* A, size_t off, int flag) {
    if (flag) return *reinterpret_cast<const bf16x8*>((const u16*)A + off);
    const float* f = (const float*)A + off;
    float4 a = *reinterpret_cast<const float4*>(f);
    float4 b = *reinterpret_cast<const float4*>(f + 4);
    bf16x8 r;
    r[0] = (__bf16)a.x; r[1] = (__bf16)a.y; r[2] = (__bf16)a.z; r[3] = (__bf16)a.w;
    r[4] = (__bf16)b.x; r[5] = (__bf16)b.y; r[6] = (__bf16)b.z; r[7] = (__bf16)b.w;
    return r;
}

// ---------------- dtype detection ----------------
__global__ void k_detect(const u32* __restrict__ x, int* __restrict__ flag) {
    int lane = threadIdx.x;
    u32 u = x[lane];
    int e = (u >> 7) & 0xFF;
    int hit = (e >= 100 && e <= 145) ? 1 : 0;
    unsigned long long b = __ballot(hit);
    if (lane == 0) flag[0] = (__popcll(b) >= 32) ? 1 : 0;
}

// ---------------- weight conversion ----------------
struct ConvJob { const void* src; float* dst; int n; };
struct ConvJobs { ConvJob j[12]; };

__global__ void k_wconv(ConvJobs jobs, const int* __restrict__ flagp) {
    const int f = *flagp;
    const int stride = gridDim.x * blockDim.x;
    for (int s = 0; s < 12; ++s) {
        const ConvJob jb = jobs.j[s];
        for (int i = blockIdx.x * blockDim.x + threadIdx.x; i < jb.n; i += stride)
            jb.dst[i] = loadx(jb.src, i, f);
    }
}

struct TJob { const float* W; u16* WT; int K, NC; };
struct TJobs { TJob j[5]; };

__global__ void k_wtrans(TJobs jobs) {
    const int stride = gridDim.x * blockDim.x;
    for (int s = 0; s < 5; ++s) {
        const TJob jb = jobs.j[s];
        const int tot = jb.K * jb.NC;
        for (int i = blockIdx.x * blockDim.x + threadIdx.x; i < tot; i += stride) {
            int k = i / jb.NC, n = i - k * jb.NC;
            jb.WT[n * jb.K + k] = f2bf(jb.W[i]);
        }
    }
}

// ---------------- graph preprocessing: block-chunk radix binning ----------------
static const int CAPSH = 12;        // 4096 entries per (g,bucket) cell (avg fill ~2045)
static const int OVCAP = 65536;     // overflow list capacity (never hit for uniform input)

__global__ __launch_bounds__(256) void k_bin(const int* __restrict__ ei0, const int* __restrict__ ei1,
                                             int* __restrict__ cur, u32* __restrict__ stage,
                                             int2* __restrict__ ov, int* __restrict__ ocnt,
                                             int E, int NB, int nblk) {
    const int g = blockIdx.y;
    const int* ei = g ? ei1 : ei0;
    const int chunk = (E + nblk - 1) / nblk;
    const int e0 = blockIdx.x * chunk;
    const int e1 = (e0 + chunk < E) ? e0 + chunk : E;
    const int tid = threadIdx.x;
    __shared__ int h[512];
    __shared__ int lb[512];
    for (int i = tid; i < NB; i += 256) h[i] = 0;
    __syncthreads();
    for (int e = e0 + tid; e < e1; e += 256) {
        int d = __builtin_nontemporal_load(ei + E + e);
        atomicAdd(&h[d >> 7], 1);
    }
    __syncthreads();
    for (int b = tid; b < NB; b += 256) {
        int c = h[b];
        lb[b] = c ? atomicAdd(&cur[g * NB + b], c) : 0;
    }
    __syncthreads();
    for (int i = tid; i < NB; i += 256) h[i] = 0;
    __syncthreads();
    for (int e = e0 + tid; e < e1; e += 256) {
        int s = __builtin_nontemporal_load(ei + e);
        int d = ei[E + e];  // re-read: L2-resident from pass 1
        int b = d >> 7;
        int p = lb[b] + atomicAdd(&h[b], 1);
        if (p < (1 << CAPSH)) {
            stage[((size_t)(g * NB + b) << CAPSH) + p] = (u32)s | ((u32)(d & 127) << 16);
        } else {
            int oi = atomicAdd(ocnt, 1);
            if (oi < OVCAP) ov[oi] = make_int2(s, d | (g << 24));
        }
    }
}

__global__ __launch_bounds__(256) void k_bscan(const int* __restrict__ cur, const int2* __restrict__ ov,
                                               const int* __restrict__ ocnt, int* __restrict__ bbase,
                                               int* __restrict__ rowptr, int N, int E, int NB) {
    __shared__ int tot[2][512];
    const int tid = threadIdx.x;
    for (int g = 0; g < 2; ++g)
        for (int i = tid; i < 512; i += 256) {
            int s = 0;
            if (i < NB) {
                int cv = cur[g * NB + i];
                s = (cv < (1 << CAPSH)) ? cv : (1 << CAPSH);
            }
            tot[g][i] = s;
        }
    __syncthreads();
    int no = *ocnt; if (no > OVCAP) no = OVCAP;
    for (int i = tid; i < no; i += 256) {
        int y = ov[i].y;
        atomicAdd(&tot[y >> 24][(y & 0xFFFFFF) >> 7], 1);
    }
    __syncthreads();
    int o00 = tot[0][tid], o01 = tot[0][tid + 256];
    int o10 = tot[1][tid], o11 = tot[1][tid + 256];
    for (int off = 1; off < 512; off <<= 1) {
        int a0 = tot[0][tid]       + ((tid >= off)       ? tot[0][tid - off]       : 0);
        int a1 = tot[0][tid + 256] + ((tid + 256 >= off) ? tot[0][tid + 256 - off] : 0);
        int b0 = tot[1][tid]       + ((tid >= off)       ? tot[1][tid - off]       : 0);
        int b1 = tot[1][tid + 256] + ((tid + 256 >= off) ? tot[1][tid + 256 - off] : 0);
        __syncthreads();
        tot[0][tid] = a0; tot[0][tid + 256] = a1;
        tot[1][tid] = b0; tot[1][tid + 256] = b1;
        __syncthreads();
    }
    if (tid < NB)       { bbase[tid]            = tot[0][tid] - o00;       bbase[NB + tid]       = tot[1][tid] - o10; }
    if (tid + 256 < NB) { bbase[tid + 256]      = tot[0][tid + 256] - o01; bbase[NB + tid + 256] = tot[1][tid + 256] - o11; }
    if (tid == 0) {
        rowptr[N] = E;
        rowptr[(size_t)(N + 1) + N] = E;
    }
}

__global__ __launch_bounds__(256) void k_scatter(const int* __restrict__ cur, const u32* __restrict__ stage,
                                                 const int2* __restrict__ ov, const int* __restrict__ ocnt,
                                                 const int* __restrict__ bbase, int* __restrict__ rowptr,
                                                 float* __restrict__ dinv, int* __restrict__ csr,
                                                 int N, int E, int NB) {
    const int g = blockIdx.y, b = blockIdx.x, tid = threadIdx.x;
    const int lo = b << 7;
    int R = N - lo; if (R > 128) R = 128;
    __shared__ int hist[128], scn[128], curs[128];
    if (tid < 128) hist[tid] = 0;
    __syncthreads();
    int cv = cur[g * NB + b];
    const int n = (cv < (1 << CAPSH)) ? cv : (1 << CAPSH);
    const u32* sp = stage + ((size_t)(g * NB + b) << CAPSH);
    for (int i = tid; i < n; i += 256) atomicAdd(&hist[sp[i] >> 16], 1);
    int no = *ocnt; if (no > OVCAP) no = OVCAP;
    for (int i = tid; i < no; i += 256) {
        int y = ov[i].y;
        if ((y >> 24) != g) continue;
        int d = y & 0xFFFFFF;
        if (d >= lo && d < lo + 128) atomicAdd(&hist[d - lo], 1);
    }
    __syncthreads();
    int orig = (tid < 128) ? hist[tid] : 0;
    if (tid < 128) scn[tid] = orig;
    __syncthreads();
    for (int off = 1; off < 128; off <<= 1) {
        int v = 0;
        if (tid < 128) v = scn[tid] + ((tid >= off) ? scn[tid - off] : 0);
        __syncthreads();
        if (tid < 128) scn[tid] = v;
        __syncthreads();
    }
    const int base = bbase[g * NB + b];
    if (tid < R) {
        int ex = base + scn[tid] - orig;   // exclusive prefix
        rowptr[(size_t)g * (N + 1) + lo + tid] = ex;
        curs[tid] = ex;
        dinv[(size_t)g * N + lo + tid] = rsqrtf((float)(orig + 1));  // +1 self loop
    }
    __syncthreads();
    int* out = csr + (size_t)g * E;
    for (int i = tid; i < n; i += 256) {
        u32 v = sp[i];
        int pos = atomicAdd(&curs[v >> 16], 1);
        out[pos] = (int)(v & 0xFFFFu);
    }
    for (int i = tid; i < no; i += 256) {
        int y = ov[i].y;
        if ((y >> 24) != g) continue;
        int d = y & 0xFFFFFF;
        if (d >= lo && d < lo + 128) {
            int pos = atomicAdd(&curs[d - lo], 1);
            out[pos] = ov[i].x;
        }
    }
}

// ---------------- MFMA GEMM ----------------
// SCALE: multiply output row by dvp[g*M+row] (pre-scale by dinv[src] so the
// aggregation needs no per-edge weight: out[d]=dinv[d]*(sum h'[s]+h'[d])).
template <int K, int NC, bool AEXT, bool BIAS, bool RELU, bool NORM, bool OEXT, bool SCALE>
__global__ __launch_bounds__(256) void k_mgemm(const void* __restrict__ A0, const void* __restrict__ A1,
                                               size_t astride, const u16* __restrict__ WT,
                                               const float* __restrict__ bias, void* __restrict__ outv,
                                               size_t out_off, size_t ostride, int M,
                                               const int* __restrict__ flagp,
                                               const float* __restrict__ dvp) {
    constexpr int NT = NC / 16;
    constexpr int KI = K / 32;
    const int flag = *flagp;
    const int g = blockIdx.y;
    const void* Av = g ? A1 : A0;
    const int lane = threadIdx.x & 63;
    const int wave = threadIdx.x >> 6;
    const int q = lane >> 4;
    const int c = lane & 15;
    const int m0 = blockIdx.x * 64 + wave * 16;
    int arow = m0 + c;
    if (arow > M - 1) arow = M - 1;
    const size_t abase = (size_t)g * astride + (size_t)arow * K;

    bf16x8 afr[KI];
#pragma unroll
    for (int ki = 0; ki < KI; ++ki) {
        size_t off = abase + (size_t)ki * 32 + q * 8;
        if (AEXT) afr[ki] = load_afrag_ext(Av, off, flag);
        else      afr[ki] = *reinterpret_cast<const bf16x8*>((const u16*)Av + off);
    }

    f32x4 acc[NT];
#pragma unroll
    for (int t = 0; t < NT; ++t) acc[t] = (f32x4){0.f, 0.f, 0.f, 0.f};

#pragma unroll
    for (int ki = 0; ki < KI; ++ki) {
#pragma unroll
        for (int t = 0; t < NT; ++t) {
            const u16* bptr = WT + (size_t)(t * 16 + c) * K + ki * 32 + q * 8;
            bf16x8 bfr = *reinterpret_cast<const bf16x8*>(bptr);
            acc[t] = __builtin_amdgcn_mfma_f32_16x16x32_bf16(afr[ki], bfr, acc[t], 0, 0, 0);
        }
    }

#pragma unroll
    for (int t = 0; t < NT; ++t) {
        float bv = BIAS ? bias[t * 16 + c] : 0.f;
#pragma unroll
        for (int r = 0; r < 4; ++r) {
            float v = acc[t][r] + bv;
            if (RELU) v = fmaxf(v, 0.f);
            acc[t][r] = v;
        }
    }

    if constexpr (NORM) {
        float ss[4] = {0.f, 0.f, 0.f, 0.f};
#pragma unroll
        for (int t = 0; t < NT; ++t)
#pragma unroll
            for (int r = 0; r < 4; ++r) ss[r] += acc[t][r] * acc[t][r];
#pragma unroll
        for (int r = 0; r < 4; ++r) {
#pragma unroll
            for (int m = 1; m < 16; m <<= 1) ss[r] += __shfl_xor(ss[r], m, 64);
            float s = 1.f / fmaxf(sqrtf(ss[r]), 1e-12f);
#pragma unroll
            for (int t = 0; t < NT; ++t) acc[t][r] *= s;
        }
    }

    const size_t obase = out_off + (size_t)g * ostride;
#pragma unroll
    for (int r = 0; r < 4; ++r) {
        const int grow = m0 + q * 4 + r;
        if (grow < M) {
            float sc = 1.f;
            if constexpr (SCALE) sc = dvp[(size_t)g * M + grow];
#pragma unroll
            for (int t = 0; t < NT; ++t) {
                float v = SCALE ? acc[t][r] * sc : acc[t][r];
                size_t oi = obase + (size_t)grow * NC + t * 16 + c;
                if (OEXT) storex(outv, oi, v, flag);
                else      ((u16*)outv)[oi] = f2bf(v);
            }
        }
    }
}

// ---------------- GCN aggregation ----------------
// H pre-scaled by dinv[src]; out = relu(dinv[node]*(sum h'[s] + h'[node]) + b).
// k_agg128: pair-gather — 32 lanes x uint2(8B) = one 256B row, so ONE VMEM
// instruction fetches TWO edges' rows (halves of the wave handle different
// edges). Halves' partial sums merged with one shfl_xor(32) at the end.
__global__ __launch_bounds__(256) void k_agg128(const u32* __restrict__ H, const int* __restrict__ rowptr,
                                                const int* __restrict__ csr, const float* __restrict__ dinv,
                                                const float* __restrict__ bias, u32* __restrict__ out,
                                                int N, int E) {
    const int g = blockIdx.y;
    const int node = blockIdx.x * 4 + (threadIdx.x >> 6);
    if (node >= N) return;
    const int lane = threadIdx.x & 63;
    const int half = lane >> 5;
    const int w = lane & 31;
    const u32* h2 = H + (size_t)g * N * 64 + 2 * w;
    const int* rp = rowptr + (size_t)g * (N + 1);
    const int* cs = csr + (size_t)g * E;
    const float dn = dinv[(size_t)g * N + node];
    int e = rp[node];
    const int end = rp[node + 1];
    float a0 = 0.f, a1 = 0.f, a2 = 0.f, a3 = 0.f;
    if (half == 0) {
        uint2 sv = *reinterpret_cast<const uint2*>(h2 + (size_t)node * 64);
        a0 = bflo(sv.x); a1 = bfhi(sv.x); a2 = bflo(sv.y); a3 = bfhi(sv.y);
    }
    while (e < end) {
        int cnt = end - e; if (cnt > 64) cnt = 64;
        int my = (lane < cnt) ? cs[e + lane] : 0;
        int j = 0;
        for (; j + 8 <= cnt; j += 8) {
            int s0 = __shfl(my, j + half, 64);
            int s1 = __shfl(my, j + 2 + half, 64);
            int s2 = __shfl(my, j + 4 + half, 64);
            int s3 = __shfl(my, j + 6 + half, 64);
            uint2 h0 = *reinterpret_cast<const uint2*>(h2 + (size_t)s0 * 64);
            uint2 h1 = *reinterpret_cast<const uint2*>(h2 + (size_t)s1 * 64);
            uint2 hh2 = *reinterpret_cast<const uint2*>(h2 + (size_t)s2 * 64);
            uint2 h3 = *reinterpret_cast<const uint2*>(h2 + (size_t)s3 * 64);
            a0 += bflo(h0.x); a1 += bfhi(h0.x); a2 += bflo(h0.y); a3 += bfhi(h0.y);
            a0 += bflo(h1.x); a1 += bfhi(h1.x); a2 += bflo(h1.y); a3 += bfhi(h1.y);
            a0 += bflo(hh2.x); a1 += bfhi(hh2.x); a2 += bflo(hh2.y); a3 += bfhi(hh2.y);
            a0 += bflo(h3.x); a1 += bfhi(h3.x); a2 += bflo(h3.y); a3 += bfhi(h3.y);
        }
        for (; j < cnt; j += 2) {
            int idx = j + half;
            int src = __shfl(my, idx < cnt ? idx : 0, 64);
            if (idx < cnt) {
                uint2 hv = *reinterpret_cast<const uint2*>(h2 + (size_t)src * 64);
                a0 += bflo(hv.x); a1 += bfhi(hv.x); a2 += bflo(hv.y); a3 += bfhi(hv.y);
            }
        }
        e += cnt;
    }
    a0 += __shfl_xor(a0, 32, 64);
    a1 += __shfl_xor(a1, 32, 64);
    a2 += __shfl_xor(a2, 32, 64);
    a3 += __shfl_xor(a3, 32, 64);
    // lane (half,w) stores u32 idx 2w+half = channels {4w+2*half, 4w+2*half+1}
    float x = half ? a2 : a0;
    float y = half ? a3 : a1;
    const int c0 = 4 * w + 2 * half;
    float r0 = fmaxf(x * dn + bias[c0], 0.f);
    float r1 = fmaxf(y * dn + bias[c0 + 1], 0.f);
    out[((size_t)g * N + node) * 64 + 2 * w + half] = pack2(r0, r1);
}

// k_agg64: quad-gather — 16 lanes x uint2(8B) = one 128B row, FOUR edges per
// VMEM instruction. Quads merged with shfl_xor(16)+shfl_xor(32).
__global__ __launch_bounds__(256) void k_agg64(const u32* __restrict__ H, const int* __restrict__ rowptr,
                                               const int* __restrict__ csr, const float* __restrict__ dinv,
                                               const float* __restrict__ bias, u32* __restrict__ out,
                                               int N, int E) {
    const int g = blockIdx.y;
    const int node = blockIdx.x * 4 + (threadIdx.x >> 6);
    if (node >= N) return;
    const int lane = threadIdx.x & 63;
    const int quad = lane >> 4;
    const int w = lane & 15;
    const u32* h2 = H + (size_t)g * N * 32 + 2 * w;
    const int* rp = rowptr + (size_t)g * (N + 1);
    const int* cs = csr + (size_t)g * E;
    const float dn = dinv[(size_t)g * N + node];
    int e = rp[node];
    const int end = rp[node + 1];
    float a0 = 0.f, a1 = 0.f, a2 = 0.f, a3 = 0.f;
    if (quad == 0) {
        uint2 sv = *reinterpret_cast<const uint2*>(h2 + (size_t)node * 32);
        a0 = bflo(sv.x); a1 = bfhi(sv.x); a2 = bflo(sv.y); a3 = bfhi(sv.y);
    }
    while (e < end) {
        int cnt = end - e; if (cnt > 64) cnt = 64;
        int my = (lane < cnt) ? cs[e + lane] : 0;
        int j = 0;
        for (; j + 16 <= cnt; j += 16) {
            int s0 = __shfl(my, j + quad, 64);
            int s1 = __shfl(my, j + 4 + quad, 64);
            int s2 = __shfl(my, j + 8 + quad, 64);
            int s3 = __shfl(my, j + 12 + quad, 64);
            uint2 h0 = *reinterpret_cast<const uint2*>(h2 + (size_t)s0 * 32);
            uint2 h1 = *reinterpret_cast<const uint2*>(h2 + (size_t)s1 * 32);
            uint2 hh2 = *reinterpret_cast<const uint2*>(h2 + (size_t)s2 * 32);
            uint2 h3 = *reinterpret_cast<const uint2*>(h2 + (size_t)s3 * 32);
            a0 += bflo(h0.x); a1 += bfhi(h0.x); a2 += bflo(h0.y); a3 += bfhi(h0.y);
            a0 += bflo(h1.x); a1 += bfhi(h1.x); a2 += bflo(h1.y); a3 += bfhi(h1.y);
            a0 += bflo(hh2.x); a1 += bfhi(hh2.x); a2 += bflo(hh2.y); a3 += bfhi(hh2.y);
            a0 += bflo(h3.x); a1 += bfhi(h3.x); a2 += bflo(h3.y); a3 += bfhi(h3.y);
        }
        for (; j < cnt; j += 4) {
            int idx = j + quad;
            int src = __shfl(my, idx < cnt ? idx : 0, 64);
            if (idx < cnt) {
                uint2 hv = *reinterpret_cast<const uint2*>(h2 + (size_t)src * 32);
                a0 += bflo(hv.x); a1 += bfhi(hv.x); a2 += bflo(hv.y); a3 += bfhi(hv.y);
            }
        }
        e += cnt;
    }
    a0 += __shfl_xor(a0, 16, 64); a0 += __shfl_xor(a0, 32, 64);
    a1 += __shfl_xor(a1, 16, 64); a1 += __shfl_xor(a1, 32, 64);
    a2 += __shfl_xor(a2, 16, 64); a2 += __shfl_xor(a2, 32, 64);
    a3 += __shfl_xor(a3, 16, 64); a3 += __shfl_xor(a3, 32, 64);
    if (quad < 2) {
        float x = quad ? a2 : a0;
        float y = quad ? a3 : a1;
        const int c0 = 4 * w + 2 * quad;
        float r0 = fmaxf(x * dn + bias[c0], 0.f);
        float r1 = fmaxf(y * dn + bias[c0 + 1], 0.f);
        out[((size_t)g * N + node) * 32 + 2 * w + quad] = pack2(r0, r1);
    }
}

// ---------------- cluster head ----------------
__global__ __launch_bounds__(256) void k_clus(const u16* __restrict__ v, const float* __restrict__ Wc2,
                                              const float* __restrict__ bc2, void* __restrict__ outv,
                                              size_t out_off, size_t ostride, int N,
                                              const int* __restrict__ flagp) {
    const int g = blockIdx.y;
    const int node = blockIdx.x * 4 + (threadIdx.x >> 6);
    if (node >= N) return;
    const int flag = *flagp;
    const int lane = threadIdx.x & 63;
    float ul = bf2f(v[((size_t)g * N + node) * 64 + lane]);
    float a0 = ul * Wc2[lane * 3 + 0];
    float a1 = ul * Wc2[lane * 3 + 1];
    float a2 = ul * Wc2[lane * 3 + 2];
#pragma unroll
    for (int m = 1; m < 64; m <<= 1) {
        a0 += __shfl_xor(a0, m, 64);
        a1 += __shfl_xor(a1, m, 64);
        a2 += __shfl_xor(a2, m, 64);
    }
    a0 += bc2[0]; a1 += bc2[1]; a2 += bc2[2];
    float mx = fmaxf(a0, fmaxf(a1, a2));
    float e0 = expf(a0 - mx), e1 = expf(a1 - mx), e2 = expf(a2 - mx);
    float inv = 1.f / (e0 + e1 + e2);
    if (lane < 3) {
        float r = (lane == 0) ? e0 : ((lane == 1) ? e1 : e2);
        storex(outv, out_off + (size_t)g * ostride + (size_t)node * 3 + lane, r * inv, flag);
    }
}

// ---------------- launcher ----------------
extern "C" void kernel_launch(void* const* d_in, const int* in_sizes, int n_in,
                              void* d_out, int out_size, void* d_ws, size_t ws_size,
                              hipStream_t stream) {
    const int N = in_sizes[0] / 128;   // 50000
    const int E = in_sizes[1] / 2;     // 800000
    const int* ei0 = (const int*)d_in[1];
    const int* ei1 = (const int*)d_in[3];
    const int NB = (N + 127) >> 7;     // 391 buckets of 128 nodes

    size_t off = 0;
    auto alloc = [&](size_t bytes) -> void* {
        void* p = (char*)d_ws + off;
        off += (bytes + 255) & ~(size_t)255;
        return p;
    };
    int* flag = (int*)alloc(256);
    const int wcnt[12] = {128 * 128, 128, 128 * 64, 64, 64 * 64, 64, 64 * 128, 128, 64 * 64, 64, 64 * 3, 3};
    float* wf[12];
    for (int i = 0; i < 12; ++i) wf[i] = (float*)alloc((size_t)wcnt[i] * 4);
    float* b1f = wf[1]; float* b2f = wf[3]; float* bp1f = wf[5]; float* bp2f = wf[7];
    float* bc1f = wf[9]; float* Wc2f = wf[10]; float* bc2f = wf[11];
    u16* W1T  = (u16*)alloc(128 * 128 * 2);
    u16* W2T  = (u16*)alloc(64 * 128 * 2);
    u16* Wp1T = (u16*)alloc(64 * 64 * 2);
    u16* Wp2T = (u16*)alloc(128 * 64 * 2);
    u16* Wc1T = (u16*)alloc(64 * 64 * 2);

    const int ncell = 2 * NB;
    int* cur    = (int*)alloc((size_t)(ncell + 1) * 4);   // +1: overflow count
    int* ocnt   = cur + ncell;
    int2* ov    = (int2*)alloc((size_t)OVCAP * 8);
    u32* stage  = (u32*)alloc(((size_t)ncell << CAPSH) * 4);
    int* bbase  = (int*)alloc((size_t)2 * NB * 4);
    int* rowptr = (int*)alloc((size_t)2 * (N + 1) * 4);
    float* dinv = (float*)alloc((size_t)2 * N * 4);
    int* csr    = (int*)alloc((size_t)2 * E * 4);
    u16* A1 = (u16*)alloc((size_t)2 * N * 128 * 2);
    u16* H2 = A1;
    u16* Qb = (u16*)alloc((size_t)2 * N * 128 * 2);
    u16* U  = Qb;
    u16* Z  = (u16*)alloc((size_t)2 * N * 64 * 2);
    (void)ws_size; (void)n_in; (void)out_size;

    k_detect<<<1, 64, 0, stream>>>((const u32*)d_in[0], flag);
    ConvJobs jobs;
    for (int i = 0; i < 12; ++i) jobs.j[i] = ConvJob{d_in[4 + i], wf[i], wcnt[i]};
    k_wconv<<<64, 256, 0, stream>>>(jobs, flag);
    TJobs tj;
    tj.j[0] = TJob{wf[0], W1T, 128, 128};
    tj.j[1] = TJob{wf[2], W2T, 128, 64};
    tj.j[2] = TJob{wf[4], Wp1T, 64, 64};
    tj.j[3] = TJob{wf[6], Wp2T, 64, 128};
    tj.j[4] = TJob{wf[8], Wc1T, 64, 64};
    k_wtrans<<<40, 256, 0, stream>>>(tj);

    hipMemsetAsync(cur, 0, (size_t)(ncell + 1) * 4, stream);
    const int NBLK = 128;   // per-graph blocks: chunk ~6250 edges -> runs of ~16 (1 line)
    k_bin<<<dim3(NBLK, 2), 256, 0, stream>>>(ei0, ei1, cur, stage, ov, ocnt, E, NB, NBLK);
    k_bscan<<<1, 256, 0, stream>>>(cur, ov, ocnt, bbase, rowptr, N, E, NB);
    k_scatter<<<dim3(NB, 2), 256, 0, stream>>>(cur, stage, ov, ocnt, bbase, rowptr, dinv, csr, N, E, NB);

    const dim3 gM((N + 63) / 64, 2);
    const dim3 gA((N + 3) / 4, 2);

    // layer 1 (output pre-scaled by dinv[row])
    k_mgemm<128, 128, true, false, false, false, false, true><<<gM, 256, 0, stream>>>(
        d_in[0], d_in[2], 0, W1T, nullptr, A1, 0, (size_t)N * 128, N, flag, dinv);
    k_agg128<<<gA, 256, 0, stream>>>((const u32*)A1, rowptr, csr, dinv, b1f, (u32*)Qb, N, E);
    // layer 2 (output pre-scaled by dinv[row])
    k_mgemm<128, 64, false, false, false, false, false, true><<<gM, 256, 0, stream>>>(
        Qb, Qb, (size_t)N * 128, W2T, nullptr, H2, 0, (size_t)N * 64, N, flag, dinv);
    k_agg64<<<gA, 256, 0, stream>>>((const u32*)H2, rowptr, csr, dinv, b2f, (u32*)Z, N, E);

    // instance head
    k_mgemm<64, 64, false, true, true, false, false, false><<<gM, 256, 0, stream>>>(
        Z, Z, (size_t)N * 64, Wp1T, bp1f, U, 0, (size_t)N * 64, N, flag, nullptr);
    k_mgemm<64, 128, false, true, false, true, true, false><<<gM, 256, 0, stream>>>(
        U, U, (size_t)N * 64, Wp2T, bp2f, d_out, 0, (size_t)N * 128, N, flag, nullptr);
    // cluster head
    k_mgemm<64, 64, false, true, true, false, false, false><<<gM, 256, 0, stream>>>(
        Z, Z, (size_t)N * 64, Wc1T, bc1f, U, 0, (size_t)N * 64, N, flag, nullptr);
    k_clus<<<gA, 256, 0, stream>>>(U, Wc2f, bc2f, d_out,
                                   (size_t)2 * N * 128, (size_t)N * 3, N, flag);
}

// Round 7
// 406.036 us; speedup vs baseline: 1.2616x; 1.0177x over previous
//
#include <hip/hip_runtime.h>
#include <cstdint>
#include <cstddef>

using u16 = unsigned short;
using u32 = unsigned int;

typedef __bf16 bf16x8 __attribute__((ext_vector_type(8)));
typedef float  f32x4  __attribute__((ext_vector_type(4)));

__device__ __forceinline__ float bf2f(u16 b) { union { u32 i; float f; } v; v.i = ((u32)b) << 16; return v.f; }
__device__ __forceinline__ u16 f2bf(float f) { __bf16 b = (__bf16)f; return __builtin_bit_cast(u16, b); }
__device__ __forceinline__ float bflo(u32 u) { union { u32 i; float f; } v; v.i = u << 16; return v.f; }
__device__ __forceinline__ float bfhi(u32 u) { union { u32 i; float f; } v; v.i = u & 0xffff0000u; return v.f; }
__device__ __forceinline__ u32 pack2(float a, float b) { return (u32)f2bf(a) | ((u32)f2bf(b) << 16); }

// v_dot2_f32_bf16 with a channel-selector: acc += bf16(lo or hi of hv).
// sel = 0x00003f80 (bf16 1.0 in lane0) -> low channel; 0x3f800000 -> high.
__device__ __forceinline__ void dot2acc(float& acc, u32 hv, u32 sel) {
    asm("v_dot2_f32_bf16 %0, %1, %2, %0" : "+v"(acc) : "v"(hv), "v"(sel));
}

__device__ __forceinline__ float loadx(const void* p, size_t i, int flag_bf16) {
    return flag_bf16 ? bf2f(((const u16*)p)[i]) : ((const float*)p)[i];
}
__device__ __forceinline__ void storex(void* p, size_t i, float v, int flag_bf16) {
    if (flag_bf16) ((u16*)p)[i] = f2bf(v);
    else           ((float*)p)[i] = v;
}

__device__ __forceinline__ bf16x8 load_afrag_ext(const void* A, size_t off, int flag) {
    if (flag) return *reinterpret_cast<const bf16x8*>((const u16*)A + off);
    const float* f = (const float*)A + off;
    float4 a = *reinterpret_cast<const float4*>(f);
    float4 b = *reinterpret_cast<const float4*>(f + 4);
    bf16x8 r;
    r[0] = (__bf16)a.x; r[1] = (__bf16)a.y; r[2] = (__bf16)a.z; r[3] = (__bf16)a.w;
    r[4] = (__bf16)b.x; r[5] = (__bf16)b.y; r[6] = (__bf16)b.z; r[7] = (__bf16)b.w;
    return r;
}

// ---------------- dtype detection ----------------
__global__ void k_detect(const u32* __restrict__ x, int* __restrict__ flag) {
    int lane = threadIdx.x;
    u32 u = x[lane];
    int e = (u >> 7) & 0xFF;
    int hit = (e >= 100 && e <= 145) ? 1 : 0;
    unsigned long long b = __ballot(hit);
    if (lane == 0) flag[0] = (__popcll(b) >= 32) ? 1 : 0;
}

// ---------------- weight conversion ----------------
struct ConvJob { const void* src; float* dst; int n; };
struct ConvJobs { ConvJob j[12]; };

__global__ void k_wconv(ConvJobs jobs, const int* __restrict__ flagp) {
    const int f = *flagp;
    const int stride = gridDim.x * blockDim.x;
    for (int s = 0; s < 12; ++s) {
        const ConvJob jb = jobs.j[s];
        for (int i = blockIdx.x * blockDim.x + threadIdx.x; i < jb.n; i += stride)
            jb.dst[i] = loadx(jb.src, i, f);
    }
}

struct TJob { const float* W; u16* WT; int K, NC; };
struct TJobs { TJob j[5]; };

__global__ void k_wtrans(TJobs jobs) {
    const int stride = gridDim.x * blockDim.x;
    for (int s = 0; s < 5; ++s) {
        const TJob jb = jobs.j[s];
        const int tot = jb.K * jb.NC;
        for (int i = blockIdx.x * blockDim.x + threadIdx.x; i < tot; i += stride) {
            int k = i / jb.NC, n = i - k * jb.NC;
            jb.WT[n * jb.K + k] = f2bf(jb.W[i]);
        }
    }
}

// ---------------- graph preprocessing: block-chunk radix binning ----------------
static const int CAPSH = 12;        // 4096 entries per (g,bucket) cell (avg fill ~2045)
static const int OVCAP = 65536;     // overflow list capacity (never hit for uniform input)

__global__ __launch_bounds__(256) void k_bin(const int* __restrict__ ei0, const int* __restrict__ ei1,
                                             int* __restrict__ cur, u32* __restrict__ stage,
                                             int2* __restrict__ ov, int* __restrict__ ocnt,
                                             int E, int NB, int nblk) {
    const int g = blockIdx.y;
    const int* ei = g ? ei1 : ei0;
    const int chunk = (E + nblk - 1) / nblk;
    const int e0 = blockIdx.x * chunk;
    const int e1 = (e0 + chunk < E) ? e0 + chunk : E;
    const int tid = threadIdx.x;
    __shared__ int h[512];
    __shared__ int lb[512];
    for (int i = tid; i < NB; i += 256) h[i] = 0;
    __syncthreads();
    for (int e = e0 + tid; e < e1; e += 256) {
        int d = __builtin_nontemporal_load(ei + E + e);
        atomicAdd(&h[d >> 7], 1);
    }
    __syncthreads();
    for (int b = tid; b < NB; b += 256) {
        int c = h[b];
        lb[b] = c ? atomicAdd(&cur[g * NB + b], c) : 0;
    }
    __syncthreads();
    for (int i = tid; i < NB; i += 256) h[i] = 0;
    __syncthreads();
    for (int e = e0 + tid; e < e1; e += 256) {
        int s = __builtin_nontemporal_load(ei + e);
        int d = ei[E + e];  // re-read: L2-resident from pass 1
        int b = d >> 7;
        int p = lb[b] + atomicAdd(&h[b], 1);
        if (p < (1 << CAPSH)) {
            stage[((size_t)(g * NB + b) << CAPSH) + p] = (u32)s | ((u32)(d & 127) << 16);
        } else {
            int oi = atomicAdd(ocnt, 1);
            if (oi < OVCAP) ov[oi] = make_int2(s, d | (g << 24));
        }
    }
}

__global__ __launch_bounds__(256) void k_bscan(const int* __restrict__ cur, const int2* __restrict__ ov,
                                               const int* __restrict__ ocnt, int* __restrict__ bbase,
                                               int* __restrict__ rowptr, int N, int E, int NB) {
    __shared__ int tot[2][512];
    const int tid = threadIdx.x;
    for (int g = 0; g < 2; ++g)
        for (int i = tid; i < 512; i += 256) {
            int s = 0;
            if (i < NB) {
                int cv = cur[g * NB + i];
                s = (cv < (1 << CAPSH)) ? cv : (1 << CAPSH);
            }
            tot[g][i] = s;
        }
    __syncthreads();
    int no = *ocnt; if (no > OVCAP) no = OVCAP;
    for (int i = tid; i < no; i += 256) {
        int y = ov[i].y;
        atomicAdd(&tot[y >> 24][(y & 0xFFFFFF) >> 7], 1);
    }
    __syncthreads();
    int o00 = tot[0][tid], o01 = tot[0][tid + 256];
    int o10 = tot[1][tid], o11 = tot[1][tid + 256];
    for (int off = 1; off < 512; off <<= 1) {
        int a0 = tot[0][tid]       + ((tid >= off)       ? tot[0][tid - off]       : 0);
        int a1 = tot[0][tid + 256] + ((tid + 256 >= off) ? tot[0][tid + 256 - off] : 0);
        int b0 = tot[1][tid]       + ((tid >= off)       ? tot[1][tid - off]       : 0);
        int b1 = tot[1][tid + 256] + ((tid + 256 >= off) ? tot[1][tid + 256 - off] : 0);
        __syncthreads();
        tot[0][tid] = a0; tot[0][tid + 256] = a1;
        tot[1][tid] = b0; tot[1][tid + 256] = b1;
        __syncthreads();
    }
    if (tid < NB)       { bbase[tid]            = tot[0][tid] - o00;       bbase[NB + tid]       = tot[1][tid] - o10; }
    if (tid + 256 < NB) { bbase[tid + 256]      = tot[0][tid + 256] - o01; bbase[NB + tid + 256] = tot[1][tid + 256] - o11; }
    if (tid == 0) {
        rowptr[N] = E;
        rowptr[(size_t)(N + 1) + N] = E;
    }
}

__global__ __launch_bounds__(256) void k_scatter(const int* __restrict__ cur, const u32* __restrict__ stage,
                                                 const int2* __restrict__ ov, const int* __restrict__ ocnt,
                                                 const int* __restrict__ bbase, int* __restrict__ rowptr,
                                                 float* __restrict__ dinv, int* __restrict__ csr,
                                                 int N, int E, int NB) {
    const int g = blockIdx.y, b = blockIdx.x, tid = threadIdx.x;
    const int lo = b << 7;
    int R = N - lo; if (R > 128) R = 128;
    __shared__ int hist[128], scn[128], curs[128];
    if (tid < 128) hist[tid] = 0;
    __syncthreads();
    int cv = cur[g * NB + b];
    const int n = (cv < (1 << CAPSH)) ? cv : (1 << CAPSH);
    const u32* sp = stage + ((size_t)(g * NB + b) << CAPSH);
    for (int i = tid; i < n; i += 256) atomicAdd(&hist[sp[i] >> 16], 1);
    int no = *ocnt; if (no > OVCAP) no = OVCAP;
    for (int i = tid; i < no; i += 256) {
        int y = ov[i].y;
        if ((y >> 24) != g) continue;
        int d = y & 0xFFFFFF;
        if (d >= lo && d < lo + 128) atomicAdd(&hist[d - lo], 1);
    }
    __syncthreads();
    int orig = (tid < 128) ? hist[tid] : 0;
    if (tid < 128) scn[tid] = orig;
    __syncthreads();
    for (int off = 1; off < 128; off <<= 1) {
        int v = 0;
        if (tid < 128) v = scn[tid] + ((tid >= off) ? scn[tid - off] : 0);
        __syncthreads();
        if (tid < 128) scn[tid] = v;
        __syncthreads();
    }
    const int base = bbase[g * NB + b];
    if (tid < R) {
        int ex = base + scn[tid] - orig;   // exclusive prefix
        rowptr[(size_t)g * (N + 1) + lo + tid] = ex;
        curs[tid] = ex;
        dinv[(size_t)g * N + lo + tid] = rsqrtf((float)(orig + 1));  // +1 self loop
    }
    __syncthreads();
    int* out = csr + (size_t)g * E;
    for (int i = tid; i < n; i += 256) {
        u32 v = sp[i];
        int pos = atomicAdd(&curs[v >> 16], 1);
        out[pos] = (int)(v & 0xFFFFu);
    }
    for (int i = tid; i < no; i += 256) {
        int y = ov[i].y;
        if ((y >> 24) != g) continue;
        int d = y & 0xFFFFFF;
        if (d >= lo && d < lo + 128) {
            int pos = atomicAdd(&curs[d - lo], 1);
            out[pos] = ov[i].x;
        }
    }
}

// ---------------- MFMA GEMM ----------------
// SCALE: multiply output row by dvp[g*M+row] (pre-scale by dinv[src] so the
// aggregation needs no per-edge weight). ARS: A row stride in elements
// (0 = dense = K) — used to read a 64-col slice out of a 128-col matrix.
template <int K, int NC, bool AEXT, bool BIAS, bool RELU, bool NORM, bool OEXT, bool SCALE, int ARS>
__global__ __launch_bounds__(256) void k_mgemm(const void* __restrict__ A0, const void* __restrict__ A1,
                                               size_t astride, const u16* __restrict__ WT,
                                               const float* __restrict__ bias, void* __restrict__ outv,
                                               size_t out_off, size_t ostride, int M,
                                               const int* __restrict__ flagp,
                                               const float* __restrict__ dvp) {
    constexpr int NT = NC / 16;
    constexpr int KI = K / 32;
    constexpr int RS = (ARS == 0) ? K : ARS;
    const int flag = *flagp;
    const int g = blockIdx.y;
    const void* Av = g ? A1 : A0;
    const int lane = threadIdx.x & 63;
    const int wave = threadIdx.x >> 6;
    const int q = lane >> 4;
    const int c = lane & 15;
    const int m0 = blockIdx.x * 64 + wave * 16;
    int arow = m0 + c;
    if (arow > M - 1) arow = M - 1;
    const size_t abase = (size_t)g * astride + (size_t)arow * RS;

    bf16x8 afr[KI];
#pragma unroll
    for (int ki = 0; ki < KI; ++ki) {
        size_t off = abase + (size_t)ki * 32 + q * 8;
        if (AEXT) afr[ki] = load_afrag_ext(Av, off, flag);
        else      afr[ki] = *reinterpret_cast<const bf16x8*>((const u16*)Av + off);
    }

    f32x4 acc[NT];
#pragma unroll
    for (int t = 0; t < NT; ++t) acc[t] = (f32x4){0.f, 0.f, 0.f, 0.f};

#pragma unroll
    for (int ki = 0; ki < KI; ++ki) {
#pragma unroll
        for (int t = 0; t < NT; ++t) {
            const u16* bptr = WT + (size_t)(t * 16 + c) * K + ki * 32 + q * 8;
            bf16x8 bfr = *reinterpret_cast<const bf16x8*>(bptr);
            acc[t] = __builtin_amdgcn_mfma_f32_16x16x32_bf16(afr[ki], bfr, acc[t], 0, 0, 0);
        }
    }

#pragma unroll
    for (int t = 0; t < NT; ++t) {
        float bv = BIAS ? bias[t * 16 + c] : 0.f;
#pragma unroll
        for (int r = 0; r < 4; ++r) {
            float v = acc[t][r] + bv;
            if (RELU) v = fmaxf(v, 0.f);
            acc[t][r] = v;
        }
    }

    if constexpr (NORM) {
        float ss[4] = {0.f, 0.f, 0.f, 0.f};
#pragma unroll
        for (int t = 0; t < NT; ++t)
#pragma unroll
            for (int r = 0; r < 4; ++r) ss[r] += acc[t][r] * acc[t][r];
#pragma unroll
        for (int r = 0; r < 4; ++r) {
#pragma unroll
            for (int m = 1; m < 16; m <<= 1) ss[r] += __shfl_xor(ss[r], m, 64);
            float s = 1.f / fmaxf(sqrtf(ss[r]), 1e-12f);
#pragma unroll
            for (int t = 0; t < NT; ++t) acc[t][r] *= s;
        }
    }

    const size_t obase = out_off + (size_t)g * ostride;
#pragma unroll
    for (int r = 0; r < 4; ++r) {
        const int grow = m0 + q * 4 + r;
        if (grow < M) {
            float sc = 1.f;
            if constexpr (SCALE) sc = dvp[(size_t)g * M + grow];
#pragma unroll
            for (int t = 0; t < NT; ++t) {
                float v = SCALE ? acc[t][r] * sc : acc[t][r];
                size_t oi = obase + (size_t)grow * NC + t * 16 + c;
                if (OEXT) storex(outv, oi, v, flag);
                else      ((u16*)outv)[oi] = f2bf(v);
            }
        }
    }
}

// ---------------- GCN aggregation ----------------
// H pre-scaled by dinv[src]; out = relu(dinv[node]*(sum h'[s] + h'[node]) + b).
// Inner loop uses v_dot2_f32_bf16 (1 inst per channel) instead of
// shift/and-unpack + add (2 inst per channel): ~40% VALU cut.
__global__ __launch_bounds__(256) void k_agg128(const u32* __restrict__ H, const int* __restrict__ rowptr,
                                                const int* __restrict__ csr, const float* __restrict__ dinv,
                                                const float* __restrict__ bias, u32* __restrict__ out,
                                                int N, int E) {
    const u32 SL = 0x00003f80u, SH = 0x3f800000u;   // bf16 1.0 selectors
    const int g = blockIdx.y;
    const int node = blockIdx.x * 4 + (threadIdx.x >> 6);
    if (node >= N) return;
    const int lane = threadIdx.x & 63;
    const int half = lane >> 5;
    const int w = lane & 31;
    const u32* h2 = H + (size_t)g * N * 64 + 2 * w;
    const int* rp = rowptr + (size_t)g * (N + 1);
    const int* cs = csr + (size_t)g * E;
    const float dn = dinv[(size_t)g * N + node];
    int e = rp[node];
    const int end = rp[node + 1];
    float a0 = 0.f, a1 = 0.f, a2 = 0.f, a3 = 0.f;
    if (half == 0) {
        uint2 sv = *reinterpret_cast<const uint2*>(h2 + (size_t)node * 64);
        dot2acc(a0, sv.x, SL); dot2acc(a1, sv.x, SH);
        dot2acc(a2, sv.y, SL); dot2acc(a3, sv.y, SH);
    }
    while (e < end) {
        int cnt = end - e; if (cnt > 64) cnt = 64;
        int my = (lane < cnt) ? cs[e + lane] : 0;
        int j = 0;
        for (; j + 8 <= cnt; j += 8) {
            int s0 = __shfl(my, j + half, 64);
            int s1 = __shfl(my, j + 2 + half, 64);
            int s2 = __shfl(my, j + 4 + half, 64);
            int s3 = __shfl(my, j + 6 + half, 64);
            uint2 h0 = *reinterpret_cast<const uint2*>(h2 + (size_t)s0 * 64);
            uint2 h1 = *reinterpret_cast<const uint2*>(h2 + (size_t)s1 * 64);
            uint2 hh2 = *reinterpret_cast<const uint2*>(h2 + (size_t)s2 * 64);
            uint2 h3 = *reinterpret_cast<const uint2*>(h2 + (size_t)s3 * 64);
            dot2acc(a0, h0.x, SL); dot2acc(a1, h0.x, SH); dot2acc(a2, h0.y, SL); dot2acc(a3, h0.y, SH);
            dot2acc(a0, h1.x, SL); dot2acc(a1, h1.x, SH); dot2acc(a2, h1.y, SL); dot2acc(a3, h1.y, SH);
            dot2acc(a0, hh2.x, SL); dot2acc(a1, hh2.x, SH); dot2acc(a2, hh2.y, SL); dot2acc(a3, hh2.y, SH);
            dot2acc(a0, h3.x, SL); dot2acc(a1, h3.x, SH); dot2acc(a2, h3.y, SL); dot2acc(a3, h3.y, SH);
        }
        for (; j < cnt; j += 2) {
            int idx = j + half;
            int src = __shfl(my, idx < cnt ? idx : 0, 64);
            if (idx < cnt) {
                uint2 hv = *reinterpret_cast<const uint2*>(h2 + (size_t)src * 64);
                dot2acc(a0, hv.x, SL); dot2acc(a1, hv.x, SH);
                dot2acc(a2, hv.y, SL); dot2acc(a3, hv.y, SH);
            }
        }
        e += cnt;
    }
    a0 += __shfl_xor(a0, 32, 64);
    a1 += __shfl_xor(a1, 32, 64);
    a2 += __shfl_xor(a2, 32, 64);
    a3 += __shfl_xor(a3, 32, 64);
    // lane (half,w) stores u32 idx 2w+half = channels {4w+2*half, 4w+2*half+1}
    float x = half ? a2 : a0;
    float y = half ? a3 : a1;
    const int c0 = 4 * w + 2 * half;
    float r0 = fmaxf(x * dn + bias[c0], 0.f);
    float r1 = fmaxf(y * dn + bias[c0 + 1], 0.f);
    out[((size_t)g * N + node) * 64 + 2 * w + half] = pack2(r0, r1);
}

__global__ __launch_bounds__(256) void k_agg64(const u32* __restrict__ H, const int* __restrict__ rowptr,
                                               const int* __restrict__ csr, const float* __restrict__ dinv,
                                               const float* __restrict__ bias, u32* __restrict__ out,
                                               int N, int E) {
    const u32 SL = 0x00003f80u, SH = 0x3f800000u;
    const int g = blockIdx.y;
    const int node = blockIdx.x * 4 + (threadIdx.x >> 6);
    if (node >= N) return;
    const int lane = threadIdx.x & 63;
    const int quad = lane >> 4;
    const int w = lane & 15;
    const u32* h2 = H + (size_t)g * N * 32 + 2 * w;
    const int* rp = rowptr + (size_t)g * (N + 1);
    const int* cs = csr + (size_t)g * E;
    const float dn = dinv[(size_t)g * N + node];
    int e = rp[node];
    const int end = rp[node + 1];
    float a0 = 0.f, a1 = 0.f, a2 = 0.f, a3 = 0.f;
    if (quad == 0) {
        uint2 sv = *reinterpret_cast<const uint2*>(h2 + (size_t)node * 32);
        dot2acc(a0, sv.x, SL); dot2acc(a1, sv.x, SH);
        dot2acc(a2, sv.y, SL); dot2acc(a3, sv.y, SH);
    }
    while (e < end) {
        int cnt = end - e; if (cnt > 64) cnt = 64;
        int my = (lane < cnt) ? cs[e + lane] : 0;
        int j = 0;
        for (; j + 16 <= cnt; j += 16) {
            int s0 = __shfl(my, j + quad, 64);
            int s1 = __shfl(my, j + 4 + quad, 64);
            int s2 = __shfl(my, j + 8 + quad, 64);
            int s3 = __shfl(my, j + 12 + quad, 64);
            uint2 h0 = *reinterpret_cast<const uint2*>(h2 + (size_t)s0 * 32);
            uint2 h1 = *reinterpret_cast<const uint2*>(h2 + (size_t)s1 * 32);
            uint2 hh2 = *reinterpret_cast<const uint2*>(h2 + (size_t)s2 * 32);
            uint2 h3 = *reinterpret_cast<const uint2*>(h2 + (size_t)s3 * 32);
            dot2acc(a0, h0.x, SL); dot2acc(a1, h0.x, SH); dot2acc(a2, h0.y, SL); dot2acc(a3, h0.y, SH);
            dot2acc(a0, h1.x, SL); dot2acc(a1, h1.x, SH); dot2acc(a2, h1.y, SL); dot2acc(a3, h1.y, SH);
            dot2acc(a0, hh2.x, SL); dot2acc(a1, hh2.x, SH); dot2acc(a2, hh2.y, SL); dot2acc(a3, hh2.y, SH);
            dot2acc(a0, h3.x, SL); dot2acc(a1, h3.x, SH); dot2acc(a2, h3.y, SL); dot2acc(a3, h3.y, SH);
        }
        for (; j < cnt; j += 4) {
            int idx = j + quad;
            int src = __shfl(my, idx < cnt ? idx : 0, 64);
            if (idx < cnt) {
                uint2 hv = *reinterpret_cast<const uint2*>(h2 + (size_t)src * 32);
                dot2acc(a0, hv.x, SL); dot2acc(a1, hv.x, SH);
                dot2acc(a2, hv.y, SL); dot2acc(a3, hv.y, SH);
            }
        }
        e += cnt;
    }
    a0 += __shfl_xor(a0, 16, 64); a0 += __shfl_xor(a0, 32, 64);
    a1 += __shfl_xor(a1, 16, 64); a1 += __shfl_xor(a1, 32, 64);
    a2 += __shfl_xor(a2, 16, 64); a2 += __shfl_xor(a2, 32, 64);
    a3 += __shfl_xor(a3, 16, 64); a3 += __shfl_xor(a3, 32, 64);
    if (quad < 2) {
        float x = quad ? a2 : a0;
        float y = quad ? a3 : a1;
        const int c0 = 4 * w + 2 * quad;
        float r0 = fmaxf(x * dn + bias[c0], 0.f);
        float r1 = fmaxf(y * dn + bias[c0 + 1], 0.f);
        out[((size_t)g * N + node) * 32 + 2 * w + quad] = pack2(r0, r1);
    }
}

// ---------------- cluster head ----------------
// Reads the cluster half (cols 64..127) of the fused U2[N][128] buffer.
__global__ __launch_bounds__(256) void k_clus(const u16* __restrict__ v, const float* __restrict__ Wc2,
                                              const float* __restrict__ bc2, void* __restrict__ outv,
                                              size_t out_off, size_t ostride, int N,
                                              const int* __restrict__ flagp) {
    const int g = blockIdx.y;
    const int node = blockIdx.x * 4 + (threadIdx.x >> 6);
    if (node >= N) return;
    const int flag = *flagp;
    const int lane = threadIdx.x & 63;
    float ul = bf2f(v[((size_t)g * N + node) * 128 + 64 + lane]);
    float a0 = ul * Wc2[lane * 3 + 0];
    float a1 = ul * Wc2[lane * 3 + 1];
    float a2 = ul * Wc2[lane * 3 + 2];
#pragma unroll
    for (int m = 1; m < 64; m <<= 1) {
        a0 += __shfl_xor(a0, m, 64);
        a1 += __shfl_xor(a1, m, 64);
        a2 += __shfl_xor(a2, m, 64);
    }
    a0 += bc2[0]; a1 += bc2[1]; a2 += bc2[2];
    float mx = fmaxf(a0, fmaxf(a1, a2));
    float e0 = expf(a0 - mx), e1 = expf(a1 - mx), e2 = expf(a2 - mx);
    float inv = 1.f / (e0 + e1 + e2);
    if (lane < 3) {
        float r = (lane == 0) ? e0 : ((lane == 1) ? e1 : e2);
        storex(outv, out_off + (size_t)g * ostride + (size_t)node * 3 + lane, r * inv, flag);
    }
}

// ---------------- launcher ----------------
extern "C" void kernel_launch(void* const* d_in, const int* in_sizes, int n_in,
                              void* d_out, int out_size, void* d_ws, size_t ws_size,
                              hipStream_t stream) {
    const int N = in_sizes[0] / 128;   // 50000
    const int E = in_sizes[1] / 2;     // 800000
    const int* ei0 = (const int*)d_in[1];
    const int* ei1 = (const int*)d_in[3];
    const int NB = (N + 127) >> 7;     // 391 buckets of 128 nodes

    size_t off = 0;
    auto alloc = [&](size_t bytes) -> void* {
        void* p = (char*)d_ws + off;
        off += (bytes + 255) & ~(size_t)255;
        return p;
    };
    int* flag = (int*)alloc(256);
    const int wcnt[12] = {128 * 128, 128, 128 * 64, 64, 64 * 64, 64, 64 * 128, 128, 64 * 64, 64, 64 * 3, 3};
    float* wf[12];
    for (int i = 0; i < 12; ++i) {
        if (i == 5) { wf[5] = (float*)alloc(128 * 4); continue; }   // fused [bp1;bc1]
        if (i == 9) { wf[9] = wf[5] + 64; continue; }
        wf[i] = (float*)alloc((size_t)wcnt[i] * 4);
    }
    float* b1f = wf[1]; float* b2f = wf[3]; float* bpcf = wf[5]; float* bp2f = wf[7];
    float* Wc2f = wf[10]; float* bc2f = wf[11];
    u16* W1T  = (u16*)alloc(128 * 128 * 2);
    u16* W2T  = (u16*)alloc(64 * 128 * 2);
    u16* Wp1T = (u16*)alloc(64 * 64 * 2);   // adjacent to Wc1T: fused [128][64]
    u16* Wc1T = (u16*)alloc(64 * 64 * 2);
    u16* Wp2T = (u16*)alloc(128 * 64 * 2);
    u16* WpcT = Wp1T;                       // fused head-1 weights

    const int ncell = 2 * NB;
    int* cur    = (int*)alloc((size_t)(ncell + 1) * 4);   // +1: overflow count
    int* ocnt   = cur + ncell;
    int2* ov    = (int2*)alloc((size_t)OVCAP * 8);
    u32* stage  = (u32*)alloc(((size_t)ncell << CAPSH) * 4);
    int* bbase  = (int*)alloc((size_t)2 * NB * 4);
    int* rowptr = (int*)alloc((size_t)2 * (N + 1) * 4);
    float* dinv = (float*)alloc((size_t)2 * N * 4);
    int* csr    = (int*)alloc((size_t)2 * E * 4);
    u16* A1 = (u16*)alloc((size_t)2 * N * 128 * 2);
    u16* H2 = A1;
    u16* Qb = (u16*)alloc((size_t)2 * N * 128 * 2);
    u16* U2 = Qb;                            // fused head-1 output [N][128]
    u16* Z  = (u16*)alloc((size_t)2 * N * 64 * 2);
    (void)ws_size; (void)n_in; (void)out_size;

    k_detect<<<1, 64, 0, stream>>>((const u32*)d_in[0], flag);
    ConvJobs jobs;
    for (int i = 0; i < 12; ++i) jobs.j[i] = ConvJob{d_in[4 + i], wf[i], wcnt[i]};
    k_wconv<<<64, 256, 0, stream>>>(jobs, flag);
    TJobs tj;
    tj.j[0] = TJob{wf[0], W1T, 128, 128};
    tj.j[1] = TJob{wf[2], W2T, 128, 64};
    tj.j[2] = TJob{wf[4], Wp1T, 64, 64};
    tj.j[3] = TJob{wf[8], Wc1T, 64, 64};
    tj.j[4] = TJob{wf[6], Wp2T, 64, 128};
    k_wtrans<<<40, 256, 0, stream>>>(tj);

    hipMemsetAsync(cur, 0, (size_t)(ncell + 1) * 4, stream);
    const int NBLK = 128;   // per-graph blocks: chunk ~6250 edges -> runs of ~16 (1 line)
    k_bin<<<dim3(NBLK, 2), 256, 0, stream>>>(ei0, ei1, cur, stage, ov, ocnt, E, NB, NBLK);
    k_bscan<<<1, 256, 0, stream>>>(cur, ov, ocnt, bbase, rowptr, N, E, NB);
    k_scatter<<<dim3(NB, 2), 256, 0, stream>>>(cur, stage, ov, ocnt, bbase, rowptr, dinv, csr, N, E, NB);

    const dim3 gM((N + 63) / 64, 2);
    const dim3 gA((N + 3) / 4, 2);

    // layer 1 (output pre-scaled by dinv[row])
    k_mgemm<128, 128, true, false, false, false, false, true, 0><<<gM, 256, 0, stream>>>(
        d_in[0], d_in[2], 0, W1T, nullptr, A1, 0, (size_t)N * 128, N, flag, dinv);
    k_agg128<<<gA, 256, 0, stream>>>((const u32*)A1, rowptr, csr, dinv, b1f, (u32*)Qb, N, E);
    // layer 2 (output pre-scaled by dinv[row])
    k_mgemm<128, 64, false, false, false, false, false, true, 0><<<gM, 256, 0, stream>>>(
        Qb, Qb, (size_t)N * 128, W2T, nullptr, H2, 0, (size_t)N * 64, N, flag, dinv);
    k_agg64<<<gA, 256, 0, stream>>>((const u32*)H2, rowptr, csr, dinv, b2f, (u32*)Z, N, E);

    // fused head-1: [Wp1 | Wc1] -> U2[N][128] (cols 0-63 inst, 64-127 clus)
    k_mgemm<64, 128, false, true, true, false, false, false, 0><<<gM, 256, 0, stream>>>(
        Z, Z, (size_t)N * 64, WpcT, bpcf, U2, 0, (size_t)N * 128, N, flag, nullptr);
    // instance head-2: reads U2 cols 0-63 (row stride 128)
    k_mgemm<64, 128, false, true, false, true, true, false, 128><<<gM, 256, 0, stream>>>(
        U2, U2, (size_t)N * 128, Wp2T, bp2f, d_out, 0, (size_t)N * 128, N, flag, nullptr);
    // cluster head: reads U2 cols 64-127
    k_clus<<<gA, 256, 0, stream>>>(U2, Wc2f, bc2f, d_out,
                                   (size_t)2 * N * 128, (size_t)N * 3, N, flag);
}

// Round 8
// 404.817 us; speedup vs baseline: 1.2654x; 1.0030x over previous
//
#include <hip/hip_runtime.h>
#include <cstdint>
#include <cstddef>

using u16 = unsigned short;
using u32 = unsigned int;

typedef __bf16 bf16x8 __attribute__((ext_vector_type(8)));
typedef float  f32x4  __attribute__((ext_vector_type(4)));

__device__ __forceinline__ float bf2f(u16 b) { union { u32 i; float f; } v; v.i = ((u32)b) << 16; return v.f; }
__device__ __forceinline__ u16 f2bf(float f) { __bf16 b = (__bf16)f; return __builtin_bit_cast(u16, b); }
__device__ __forceinline__ float bflo(u32 u) { union { u32 i; float f; } v; v.i = u << 16; return v.f; }
__device__ __forceinline__ float bfhi(u32 u) { union { u32 i; float f; } v; v.i = u & 0xffff0000u; return v.f; }
__device__ __forceinline__ u32 pack2(float a, float b) { return (u32)f2bf(a) | ((u32)f2bf(b) << 16); }

// v_dot2_f32_bf16 with a channel-selector: acc += bf16(lo or hi of hv).
__device__ __forceinline__ void dot2acc(float& acc, u32 hv, u32 sel) {
    asm("v_dot2_f32_bf16 %0, %1, %2, %0" : "+v"(acc) : "v"(hv), "v"(sel));
}

__device__ __forceinline__ float loadx(const void* p, size_t i, int flag_bf16) {
    return flag_bf16 ? bf2f(((const u16*)p)[i]) : ((const float*)p)[i];
}
__device__ __forceinline__ void storex(void* p, size_t i, float v, int flag_bf16) {
    if (flag_bf16) ((u16*)p)[i] = f2bf(v);
    else           ((float*)p)[i] = v;
}

__device__ __forceinline__ bf16x8 load_afrag_ext(const void* A, size_t off, int flag) {
    if (flag) return *reinterpret_cast<const bf16x8*>((const u16*)A + off);
    const float* f = (const float*)A + off;
    float4 a = *reinterpret_cast<const float4*>(f);
    float4 b = *reinterpret_cast<const float4*>(f + 4);
    bf16x8 r;
    r[0] = (__bf16)a.x; r[1] = (__bf16)a.y; r[2] = (__bf16)a.z; r[3] = (__bf16)a.w;
    r[4] = (__bf16)b.x; r[5] = (__bf16)b.y; r[6] = (__bf16)b.z; r[7] = (__bf16)b.w;
    return r;
}

// ---------------- dtype detection ----------------
__global__ void k_detect(const u32* __restrict__ x, int* __restrict__ flag) {
    int lane = threadIdx.x;
    u32 u = x[lane];
    int e = (u >> 7) & 0xFF;
    int hit = (e >= 100 && e <= 145) ? 1 : 0;
    unsigned long long b = __ballot(hit);
    if (lane == 0) flag[0] = (__popcll(b) >= 32) ? 1 : 0;
}

// ---------------- weight conversion ----------------
struct ConvJob { const void* src; float* dst; int n; };
struct ConvJobs { ConvJob j[12]; };

__global__ void k_wconv(ConvJobs jobs, const int* __restrict__ flagp) {
    const int f = *flagp;
    const int stride = gridDim.x * blockDim.x;
    for (int s = 0; s < 12; ++s) {
        const ConvJob jb = jobs.j[s];
        for (int i = blockIdx.x * blockDim.x + threadIdx.x; i < jb.n; i += stride)
            jb.dst[i] = loadx(jb.src, i, f);
    }
}

struct TJob { const float* W; u16* WT; int K, NC; };
struct TJobs { TJob j[5]; };

__global__ void k_wtrans(TJobs jobs) {
    const int stride = gridDim.x * blockDim.x;
    for (int s = 0; s < 5; ++s) {
        const TJob jb = jobs.j[s];
        const int tot = jb.K * jb.NC;
        for (int i = blockIdx.x * blockDim.x + threadIdx.x; i < tot; i += stride) {
            int k = i / jb.NC, n = i - k * jb.NC;
            jb.WT[n * jb.K + k] = f2bf(jb.W[i]);
        }
    }
}

// ---------------- graph preprocessing: block-chunk radix binning ----------------
static const int CAPSH = 12;        // 4096 entries per (g,bucket) cell (avg fill ~2045)
static const int OVCAP = 65536;     // overflow list capacity (never hit for uniform input)

__global__ __launch_bounds__(256) void k_bin(const int* __restrict__ ei0, const int* __restrict__ ei1,
                                             int* __restrict__ cur, u32* __restrict__ stage,
                                             int2* __restrict__ ov, int* __restrict__ ocnt,
                                             int E, int NB, int nblk) {
    const int g = blockIdx.y;
    const int* ei = g ? ei1 : ei0;
    const int chunk = (E + nblk - 1) / nblk;
    const int e0 = blockIdx.x * chunk;
    const int e1 = (e0 + chunk < E) ? e0 + chunk : E;
    const int tid = threadIdx.x;
    __shared__ int h[512];
    __shared__ int lb[512];
    for (int i = tid; i < NB; i += 256) h[i] = 0;
    __syncthreads();
    for (int e = e0 + tid; e < e1; e += 256) {
        int d = __builtin_nontemporal_load(ei + E + e);
        atomicAdd(&h[d >> 7], 1);
    }
    __syncthreads();
    for (int b = tid; b < NB; b += 256) {
        int c = h[b];
        lb[b] = c ? atomicAdd(&cur[g * NB + b], c) : 0;
    }
    __syncthreads();
    for (int i = tid; i < NB; i += 256) h[i] = 0;
    __syncthreads();
    for (int e = e0 + tid; e < e1; e += 256) {
        int s = __builtin_nontemporal_load(ei + e);
        int d = ei[E + e];  // re-read: L2-resident from pass 1
        int b = d >> 7;
        int p = lb[b] + atomicAdd(&h[b], 1);
        if (p < (1 << CAPSH)) {
            stage[((size_t)(g * NB + b) << CAPSH) + p] = (u32)s | ((u32)(d & 127) << 16);
        } else {
            int oi = atomicAdd(ocnt, 1);
            if (oi < OVCAP) ov[oi] = make_int2(s, d | (g << 24));
        }
    }
}

__global__ __launch_bounds__(256) void k_bscan(const int* __restrict__ cur, const int2* __restrict__ ov,
                                               const int* __restrict__ ocnt, int* __restrict__ bbase,
                                               int* __restrict__ rowptr, int N, int E, int NB) {
    __shared__ int tot[2][512];
    const int tid = threadIdx.x;
    for (int g = 0; g < 2; ++g)
        for (int i = tid; i < 512; i += 256) {
            int s = 0;
            if (i < NB) {
                int cv = cur[g * NB + i];
                s = (cv < (1 << CAPSH)) ? cv : (1 << CAPSH);
            }
            tot[g][i] = s;
        }
    __syncthreads();
    int no = *ocnt; if (no > OVCAP) no = OVCAP;
    for (int i = tid; i < no; i += 256) {
        int y = ov[i].y;
        atomicAdd(&tot[y >> 24][(y & 0xFFFFFF) >> 7], 1);
    }
    __syncthreads();
    int o00 = tot[0][tid], o01 = tot[0][tid + 256];
    int o10 = tot[1][tid], o11 = tot[1][tid + 256];
    for (int off = 1; off < 512; off <<= 1) {
        int a0 = tot[0][tid]       + ((tid >= off)       ? tot[0][tid - off]       : 0);
        int a1 = tot[0][tid + 256] + ((tid + 256 >= off) ? tot[0][tid + 256 - off] : 0);
        int b0 = tot[1][tid]       + ((tid >= off)       ? tot[1][tid - off]       : 0);
        int b1 = tot[1][tid + 256] + ((tid + 256 >= off) ? tot[1][tid + 256 - off] : 0);
        __syncthreads();
        tot[0][tid] = a0; tot[0][tid + 256] = a1;
        tot[1][tid] = b0; tot[1][tid + 256] = b1;
        __syncthreads();
    }
    if (tid < NB)       { bbase[tid]            = tot[0][tid] - o00;       bbase[NB + tid]       = tot[1][tid] - o10; }
    if (tid + 256 < NB) { bbase[tid + 256]      = tot[0][tid + 256] - o01; bbase[NB + tid + 256] = tot[1][tid + 256] - o11; }
    if (tid == 0) {
        rowptr[N] = E;
        rowptr[(size_t)(N + 1) + N] = E;
    }
}

__global__ __launch_bounds__(256) void k_scatter(const int* __restrict__ cur, const u32* __restrict__ stage,
                                                 const int2* __restrict__ ov, const int* __restrict__ ocnt,
                                                 const int* __restrict__ bbase, int* __restrict__ rowptr,
                                                 float* __restrict__ dinv, int* __restrict__ csr,
                                                 int N, int E, int NB) {
    const int g = blockIdx.y, b = blockIdx.x, tid = threadIdx.x;
    const int lo = b << 7;
    int R = N - lo; if (R > 128) R = 128;
    __shared__ int hist[128], scn[128], curs[128];
    if (tid < 128) hist[tid] = 0;
    __syncthreads();
    int cv = cur[g * NB + b];
    const int n = (cv < (1 << CAPSH)) ? cv : (1 << CAPSH);
    const u32* sp = stage + ((size_t)(g * NB + b) << CAPSH);
    for (int i = tid; i < n; i += 256) atomicAdd(&hist[sp[i] >> 16], 1);
    int no = *ocnt; if (no > OVCAP) no = OVCAP;
    for (int i = tid; i < no; i += 256) {
        int y = ov[i].y;
        if ((y >> 24) != g) continue;
        int d = y & 0xFFFFFF;
        if (d >= lo && d < lo + 128) atomicAdd(&hist[d - lo], 1);
    }
    __syncthreads();
    int orig = (tid < 128) ? hist[tid] : 0;
    if (tid < 128) scn[tid] = orig;
    __syncthreads();
    for (int off = 1; off < 128; off <<= 1) {
        int v = 0;
        if (tid < 128) v = scn[tid] + ((tid >= off) ? scn[tid - off] : 0);
        __syncthreads();
        if (tid < 128) scn[tid] = v;
        __syncthreads();
    }
    const int base = bbase[g * NB + b];
    if (tid < R) {
        int ex = base + scn[tid] - orig;   // exclusive prefix
        rowptr[(size_t)g * (N + 1) + lo + tid] = ex;
        curs[tid] = ex;
        dinv[(size_t)g * N + lo + tid] = rsqrtf((float)(orig + 1));  // +1 self loop
    }
    __syncthreads();
    int* out = csr + (size_t)g * E;
    for (int i = tid; i < n; i += 256) {
        u32 v = sp[i];
        int pos = atomicAdd(&curs[v >> 16], 1);
        out[pos] = (int)(v & 0xFFFFu);
    }
    for (int i = tid; i < no; i += 256) {
        int y = ov[i].y;
        if ((y >> 24) != g) continue;
        int d = y & 0xFFFFFF;
        if (d >= lo && d < lo + 128) {
            int pos = atomicAdd(&curs[d - lo], 1);
            out[pos] = ov[i].x;
        }
    }
}

// ---------------- MFMA GEMM ----------------
template <int K, int NC, bool AEXT, bool BIAS, bool RELU, bool NORM, bool OEXT, bool SCALE, int ARS>
__global__ __launch_bounds__(256) void k_mgemm(const void* __restrict__ A0, const void* __restrict__ A1,
                                               size_t astride, const u16* __restrict__ WT,
                                               const float* __restrict__ bias, void* __restrict__ outv,
                                               size_t out_off, size_t ostride, int M,
                                               const int* __restrict__ flagp,
                                               const float* __restrict__ dvp) {
    constexpr int NT = NC / 16;
    constexpr int KI = K / 32;
    constexpr int RS = (ARS == 0) ? K : ARS;
    const int flag = *flagp;
    const int g = blockIdx.y;
    const void* Av = g ? A1 : A0;
    const int lane = threadIdx.x & 63;
    const int wave = threadIdx.x >> 6;
    const int q = lane >> 4;
    const int c = lane & 15;
    const int m0 = blockIdx.x * 64 + wave * 16;
    int arow = m0 + c;
    if (arow > M - 1) arow = M - 1;
    const size_t abase = (size_t)g * astride + (size_t)arow * RS;

    bf16x8 afr[KI];
#pragma unroll
    for (int ki = 0; ki < KI; ++ki) {
        size_t off = abase + (size_t)ki * 32 + q * 8;
        if (AEXT) afr[ki] = load_afrag_ext(Av, off, flag);
        else      afr[ki] = *reinterpret_cast<const bf16x8*>((const u16*)Av + off);
    }

    f32x4 acc[NT];
#pragma unroll
    for (int t = 0; t < NT; ++t) acc[t] = (f32x4){0.f, 0.f, 0.f, 0.f};

#pragma unroll
    for (int ki = 0; ki < KI; ++ki) {
#pragma unroll
        for (int t = 0; t < NT; ++t) {
            const u16* bptr = WT + (size_t)(t * 16 + c) * K + ki * 32 + q * 8;
            bf16x8 bfr = *reinterpret_cast<const bf16x8*>(bptr);
            acc[t] = __builtin_amdgcn_mfma_f32_16x16x32_bf16(afr[ki], bfr, acc[t], 0, 0, 0);
        }
    }

#pragma unroll
    for (int t = 0; t < NT; ++t) {
        float bv = BIAS ? bias[t * 16 + c] : 0.f;
#pragma unroll
        for (int r = 0; r < 4; ++r) {
            float v = acc[t][r] + bv;
            if (RELU) v = fmaxf(v, 0.f);
            acc[t][r] = v;
        }
    }

    if constexpr (NORM) {
        float ss[4] = {0.f, 0.f, 0.f, 0.f};
#pragma unroll
        for (int t = 0; t < NT; ++t)
#pragma unroll
            for (int r = 0; r < 4; ++r) ss[r] += acc[t][r] * acc[t][r];
#pragma unroll
        for (int r = 0; r < 4; ++r) {
#pragma unroll
            for (int m = 1; m < 16; m <<= 1) ss[r] += __shfl_xor(ss[r], m, 64);
            float s = 1.f / fmaxf(sqrtf(ss[r]), 1e-12f);
#pragma unroll
            for (int t = 0; t < NT; ++t) acc[t][r] *= s;
        }
    }

    const size_t obase = out_off + (size_t)g * ostride;
#pragma unroll
    for (int r = 0; r < 4; ++r) {
        const int grow = m0 + q * 4 + r;
        if (grow < M) {
            float sc = 1.f;
            if constexpr (SCALE) sc = dvp[(size_t)g * M + grow];
#pragma unroll
            for (int t = 0; t < NT; ++t) {
                float v = SCALE ? acc[t][r] * sc : acc[t][r];
                size_t oi = obase + (size_t)grow * NC + t * 16 + c;
                if (OEXT) storex(outv, oi, v, flag);
                else      ((u16*)outv)[oi] = f2bf(v);
            }
        }
    }
}

// ---------------- GCN aggregation, graph-split XCD roles ----------------
// role = bid&7 -> XCD (round-robin dispatch): g = role>>2, quarter = role&3.
// Each XCD gathers from only ONE graph's H (12.8/6.4 MB): cross-XCD compulsory
// replication of H fetches halves (8x one-graph sets vs 8x both-graph sets).
// Per-node wave structure identical to the previous (58us) version.
__global__ __launch_bounds__(256) void k_agg128(const u32* __restrict__ H, const int* __restrict__ rowptr,
                                                const int* __restrict__ csr, const float* __restrict__ dinv,
                                                const float* __restrict__ bias, u32* __restrict__ out,
                                                int N, int E, int Q) {
    const u32 SL = 0x00003f80u, SH = 0x3f800000u;   // bf16 1.0 selectors
    const int bid = blockIdx.x;
    const int role = bid & 7;
    const int g = role >> 2;
    const int sub = role & 3;
    const int nl = (bid >> 3) * 4 + (threadIdx.x >> 6);
    if (nl >= Q) return;
    const int node = sub * Q + nl;
    if (node >= N) return;
    const int lane = threadIdx.x & 63;
    const int half = lane >> 5;
    const int w = lane & 31;
    const u32* h2 = H + (size_t)g * N * 64 + 2 * w;
    const int* rp = rowptr + (size_t)g * (N + 1);
    const int* cs = csr + (size_t)g * E;
    const float dn = dinv[(size_t)g * N + node];
    int e = rp[node];
    const int end = rp[node + 1];
    float a0 = 0.f, a1 = 0.f, a2 = 0.f, a3 = 0.f;
    if (half == 0) {
        uint2 sv = *reinterpret_cast<const uint2*>(h2 + (size_t)node * 64);
        dot2acc(a0, sv.x, SL); dot2acc(a1, sv.x, SH);
        dot2acc(a2, sv.y, SL); dot2acc(a3, sv.y, SH);
    }
    while (e < end) {
        int cnt = end - e; if (cnt > 64) cnt = 64;
        int my = (lane < cnt) ? cs[e + lane] : 0;
        int j = 0;
        for (; j + 8 <= cnt; j += 8) {
            int s0 = __shfl(my, j + half, 64);
            int s1 = __shfl(my, j + 2 + half, 64);
            int s2 = __shfl(my, j + 4 + half, 64);
            int s3 = __shfl(my, j + 6 + half, 64);
            uint2 h0 = *reinterpret_cast<const uint2*>(h2 + (size_t)s0 * 64);
            uint2 h1 = *reinterpret_cast<const uint2*>(h2 + (size_t)s1 * 64);
            uint2 hh2 = *reinterpret_cast<const uint2*>(h2 + (size_t)s2 * 64);
            uint2 h3 = *reinterpret_cast<const uint2*>(h2 + (size_t)s3 * 64);
            dot2acc(a0, h0.x, SL); dot2acc(a1, h0.x, SH); dot2acc(a2, h0.y, SL); dot2acc(a3, h0.y, SH);
            dot2acc(a0, h1.x, SL); dot2acc(a1, h1.x, SH); dot2acc(a2, h1.y, SL); dot2acc(a3, h1.y, SH);
            dot2acc(a0, hh2.x, SL); dot2acc(a1, hh2.x, SH); dot2acc(a2, hh2.y, SL); dot2acc(a3, hh2.y, SH);
            dot2acc(a0, h3.x, SL); dot2acc(a1, h3.x, SH); dot2acc(a2, h3.y, SL); dot2acc(a3, h3.y, SH);
        }
        for (; j < cnt; j += 2) {
            int idx = j + half;
            int src = __shfl(my, idx < cnt ? idx : 0, 64);
            if (idx < cnt) {
                uint2 hv = *reinterpret_cast<const uint2*>(h2 + (size_t)src * 64);
                dot2acc(a0, hv.x, SL); dot2acc(a1, hv.x, SH);
                dot2acc(a2, hv.y, SL); dot2acc(a3, hv.y, SH);
            }
        }
        e += cnt;
    }
    a0 += __shfl_xor(a0, 32, 64);
    a1 += __shfl_xor(a1, 32, 64);
    a2 += __shfl_xor(a2, 32, 64);
    a3 += __shfl_xor(a3, 32, 64);
    float x = half ? a2 : a0;
    float y = half ? a3 : a1;
    const int c0 = 4 * w + 2 * half;
    float r0 = fmaxf(x * dn + bias[c0], 0.f);
    float r1 = fmaxf(y * dn + bias[c0 + 1], 0.f);
    out[((size_t)g * N + node) * 64 + 2 * w + half] = pack2(r0, r1);
}

__global__ __launch_bounds__(256) void k_agg64(const u32* __restrict__ H, const int* __restrict__ rowptr,
                                               const int* __restrict__ csr, const float* __restrict__ dinv,
                                               const float* __restrict__ bias, u32* __restrict__ out,
                                               int N, int E, int Q) {
    const u32 SL = 0x00003f80u, SH = 0x3f800000u;
    const int bid = blockIdx.x;
    const int role = bid & 7;
    const int g = role >> 2;
    const int sub = role & 3;
    const int nl = (bid >> 3) * 4 + (threadIdx.x >> 6);
    if (nl >= Q) return;
    const int node = sub * Q + nl;
    if (node >= N) return;
    const int lane = threadIdx.x & 63;
    const int quad = lane >> 4;
    const int w = lane & 15;
    const u32* h2 = H + (size_t)g * N * 32 + 2 * w;
    const int* rp = rowptr + (size_t)g * (N + 1);
    const int* cs = csr + (size_t)g * E;
    const float dn = dinv[(size_t)g * N + node];
    int e = rp[node];
    const int end = rp[node + 1];
    float a0 = 0.f, a1 = 0.f, a2 = 0.f, a3 = 0.f;
    if (quad == 0) {
        uint2 sv = *reinterpret_cast<const uint2*>(h2 + (size_t)node * 32);
        dot2acc(a0, sv.x, SL); dot2acc(a1, sv.x, SH);
        dot2acc(a2, sv.y, SL); dot2acc(a3, sv.y, SH);
    }
    while (e < end) {
        int cnt = end - e; if (cnt > 64) cnt = 64;
        int my = (lane < cnt) ? cs[e + lane] : 0;
        int j = 0;
        for (; j + 16 <= cnt; j += 16) {
            int s0 = __shfl(my, j + quad, 64);
            int s1 = __shfl(my, j + 4 + quad, 64);
            int s2 = __shfl(my, j + 8 + quad, 64);
            int s3 = __shfl(my, j + 12 + quad, 64);
            uint2 h0 = *reinterpret_cast<const uint2*>(h2 + (size_t)s0 * 32);
            uint2 h1 = *reinterpret_cast<const uint2*>(h2 + (size_t)s1 * 32);
            uint2 hh2 = *reinterpret_cast<const uint2*>(h2 + (size_t)s2 * 32);
            uint2 h3 = *reinterpret_cast<const uint2*>(h2 + (size_t)s3 * 32);
            dot2acc(a0, h0.x, SL); dot2acc(a1, h0.x, SH); dot2acc(a2, h0.y, SL); dot2acc(a3, h0.y, SH);
            dot2acc(a0, h1.x, SL); dot2acc(a1, h1.x, SH); dot2acc(a2, h1.y, SL); dot2acc(a3, h1.y, SH);
            dot2acc(a0, hh2.x, SL); dot2acc(a1, hh2.x, SH); dot2acc(a2, hh2.y, SL); dot2acc(a3, hh2.y, SH);
            dot2acc(a0, h3.x, SL); dot2acc(a1, h3.x, SH); dot2acc(a2, h3.y, SL); dot2acc(a3, h3.y, SH);
        }
        for (; j < cnt; j += 4) {
            int idx = j + quad;
            int src = __shfl(my, idx < cnt ? idx : 0, 64);
            if (idx < cnt) {
                uint2 hv = *reinterpret_cast<const uint2*>(h2 + (size_t)src * 32);
                dot2acc(a0, hv.x, SL); dot2acc(a1, hv.x, SH);
                dot2acc(a2, hv.y, SL); dot2acc(a3, hv.y, SH);
            }
        }
        e += cnt;
    }
    a0 += __shfl_xor(a0, 16, 64); a0 += __shfl_xor(a0, 32, 64);
    a1 += __shfl_xor(a1, 16, 64); a1 += __shfl_xor(a1, 32, 64);
    a2 += __shfl_xor(a2, 16, 64); a2 += __shfl_xor(a2, 32, 64);
    a3 += __shfl_xor(a3, 16, 64); a3 += __shfl_xor(a3, 32, 64);
    if (quad < 2) {
        float x = quad ? a2 : a0;
        float y = quad ? a3 : a1;
        const int c0 = 4 * w + 2 * quad;
        float r0 = fmaxf(x * dn + bias[c0], 0.f);
        float r1 = fmaxf(y * dn + bias[c0 + 1], 0.f);
        out[((size_t)g * N + node) * 32 + 2 * w + quad] = pack2(r0, r1);
    }
}

// ---------------- cluster head ----------------
// Reads the cluster half (cols 64..127) of the fused U2[N][128] buffer.
__global__ __launch_bounds__(256) void k_clus(const u16* __restrict__ v, const float* __restrict__ Wc2,
                                              const float* __restrict__ bc2, void* __restrict__ outv,
                                              size_t out_off, size_t ostride, int N,
                                              const int* __restrict__ flagp) {
    const int g = blockIdx.y;
    const int node = blockIdx.x * 4 + (threadIdx.x >> 6);
    if (node >= N) return;
    const int flag = *flagp;
    const int lane = threadIdx.x & 63;
    float ul = bf2f(v[((size_t)g * N + node) * 128 + 64 + lane]);
    float a0 = ul * Wc2[lane * 3 + 0];
    float a1 = ul * Wc2[lane * 3 + 1];
    float a2 = ul * Wc2[lane * 3 + 2];
#pragma unroll
    for (int m = 1; m < 64; m <<= 1) {
        a0 += __shfl_xor(a0, m, 64);
        a1 += __shfl_xor(a1, m, 64);
        a2 += __shfl_xor(a2, m, 64);
    }
    a0 += bc2[0]; a1 += bc2[1]; a2 += bc2[2];
    float mx = fmaxf(a0, fmaxf(a1, a2));
    float e0 = expf(a0 - mx), e1 = expf(a1 - mx), e2 = expf(a2 - mx);
    float inv = 1.f / (e0 + e1 + e2);
    if (lane < 3) {
        float r = (lane == 0) ? e0 : ((lane == 1) ? e1 : e2);
        storex(outv, out_off + (size_t)g * ostride + (size_t)node * 3 + lane, r * inv, flag);
    }
}

// ---------------- launcher ----------------
extern "C" void kernel_launch(void* const* d_in, const int* in_sizes, int n_in,
                              void* d_out, int out_size, void* d_ws, size_t ws_size,
                              hipStream_t stream) {
    const int N = in_sizes[0] / 128;   // 50000
    const int E = in_sizes[1] / 2;     // 800000
    const int* ei0 = (const int*)d_in[1];
    const int* ei1 = (const int*)d_in[3];
    const int NB = (N + 127) >> 7;     // 391 buckets of 128 nodes

    size_t off = 0;
    auto alloc = [&](size_t bytes) -> void* {
        void* p = (char*)d_ws + off;
        off += (bytes + 255) & ~(size_t)255;
        return p;
    };
    int* flag = (int*)alloc(256);
    const int wcnt[12] = {128 * 128, 128, 128 * 64, 64, 64 * 64, 64, 64 * 128, 128, 64 * 64, 64, 64 * 3, 3};
    float* wf[12];
    for (int i = 0; i < 12; ++i) {
        if (i == 5) { wf[5] = (float*)alloc(128 * 4); continue; }   // fused [bp1;bc1]
        if (i == 9) { wf[9] = wf[5] + 64; continue; }
        wf[i] = (float*)alloc((size_t)wcnt[i] * 4);
    }
    float* b1f = wf[1]; float* b2f = wf[3]; float* bpcf = wf[5]; float* bp2f = wf[7];
    float* Wc2f = wf[10]; float* bc2f = wf[11];
    u16* W1T  = (u16*)alloc(128 * 128 * 2);
    u16* W2T  = (u16*)alloc(64 * 128 * 2);
    u16* Wp1T = (u16*)alloc(64 * 64 * 2);   // adjacent to Wc1T: fused [128][64]
    u16* Wc1T = (u16*)alloc(64 * 64 * 2);
    u16* Wp2T = (u16*)alloc(128 * 64 * 2);
    u16* WpcT = Wp1T;                       // fused head-1 weights

    const int ncell = 2 * NB;
    int* cur    = (int*)alloc((size_t)(ncell + 1) * 4);   // +1: overflow count
    int* ocnt   = cur + ncell;
    int2* ov    = (int2*)alloc((size_t)OVCAP * 8);
    u32* stage  = (u32*)alloc(((size_t)ncell << CAPSH) * 4);
    int* bbase  = (int*)alloc((size_t)2 * NB * 4);
    int* rowptr = (int*)alloc((size_t)2 * (N + 1) * 4);
    float* dinv = (float*)alloc((size_t)2 * N * 4);
    int* csr    = (int*)alloc((size_t)2 * E * 4);
    u16* A1 = (u16*)alloc((size_t)2 * N * 128 * 2);
    u16* H2 = A1;
    u16* Qb = (u16*)alloc((size_t)2 * N * 128 * 2);
    u16* U2 = Qb;                            // fused head-1 output [N][128]
    u16* Z  = (u16*)alloc((size_t)2 * N * 64 * 2);
    (void)ws_size; (void)n_in; (void)out_size;

    k_detect<<<1, 64, 0, stream>>>((const u32*)d_in[0], flag);
    ConvJobs jobs;
    for (int i = 0; i < 12; ++i) jobs.j[i] = ConvJob{d_in[4 + i], wf[i], wcnt[i]};
    k_wconv<<<64, 256, 0, stream>>>(jobs, flag);
    TJobs tj;
    tj.j[0] = TJob{wf[0], W1T, 128, 128};
    tj.j[1] = TJob{wf[2], W2T, 128, 64};
    tj.j[2] = TJob{wf[4], Wp1T, 64, 64};
    tj.j[3] = TJob{wf[8], Wc1T, 64, 64};
    tj.j[4] = TJob{wf[6], Wp2T, 64, 128};
    k_wtrans<<<40, 256, 0, stream>>>(tj);

    hipMemsetAsync(cur, 0, (size_t)(ncell + 1) * 4, stream);
    const int NBLK = 128;   // per-graph blocks: chunk ~6250 edges -> runs of ~16 (1 line)
    k_bin<<<dim3(NBLK, 2), 256, 0, stream>>>(ei0, ei1, cur, stage, ov, ocnt, E, NB, NBLK);
    k_bscan<<<1, 256, 0, stream>>>(cur, ov, ocnt, bbase, rowptr, N, E, NB);
    k_scatter<<<dim3(NB, 2), 256, 0, stream>>>(cur, stage, ov, ocnt, bbase, rowptr, dinv, csr, N, E, NB);

    const dim3 gM((N + 63) / 64, 2);
    const dim3 gA((N + 3) / 4, 2);
    const int Q = (N + 3) / 4;               // nodes per quarter-role
    const dim3 gAgg(8 * ((Q + 3) / 4));      // role = bid&7 -> (g, quarter) on one XCD

    // layer 1 (output pre-scaled by dinv[row])
    k_mgemm<128, 128, true, false, false, false, false, true, 0><<<gM, 256, 0, stream>>>(
        d_in[0], d_in[2], 0, W1T, nullptr, A1, 0, (size_t)N * 128, N, flag, dinv);
    k_agg128<<<gAgg, 256, 0, stream>>>((const u32*)A1, rowptr, csr, dinv, b1f, (u32*)Qb, N, E, Q);
    // layer 2 (output pre-scaled by dinv[row])
    k_mgemm<128, 64, false, false, false, false, false, true, 0><<<gM, 256, 0, stream>>>(
        Qb, Qb, (size_t)N * 128, W2T, nullptr, H2, 0, (size_t)N * 64, N, flag, dinv);
    k_agg64<<<gAgg, 256, 0, stream>>>((const u32*)H2, rowptr, csr, dinv, b2f, (u32*)Z, N, E, Q);

    // fused head-1: [Wp1 | Wc1] -> U2[N][128] (cols 0-63 inst, 64-127 clus)
    k_mgemm<64, 128, false, true, true, false, false, false, 0><<<gM, 256, 0, stream>>>(
        Z, Z, (size_t)N * 64, WpcT, bpcf, U2, 0, (size_t)N * 128, N, flag, nullptr);
    // instance head-2: reads U2 cols 0-63 (row stride 128)
    k_mgemm<64, 128, false, true, false, true, true, false, 128><<<gM, 256, 0, stream>>>(
        U2, U2, (size_t)N * 128, Wp2T, bp2f, d_out, 0, (size_t)N * 128, N, flag, nullptr);
    // cluster head: reads U2 cols 64-127
    k_clus<<<gA, 256, 0, stream>>>(U2, Wc2f, bc2f, d_out,
                                   (size_t)2 * N * 128, (size_t)N * 3, N, flag);
}

// Round 9
// 396.023 us; speedup vs baseline: 1.2935x; 1.0222x over previous
//
#include <hip/hip_runtime.h>
#include <cstdint>
#include <cstddef>

using u16 = unsigned short;
using u32 = unsigned int;

typedef __bf16 bf16x8 __attribute__((ext_vector_type(8)));
typedef float  f32x4  __attribute__((ext_vector_type(4)));

__device__ __forceinline__ float bf2f(u16 b) { union { u32 i; float f; } v; v.i = ((u32)b) << 16; return v.f; }
__device__ __forceinline__ u16 f2bf(float f) { __bf16 b = (__bf16)f; return __builtin_bit_cast(u16, b); }
__device__ __forceinline__ float bflo(u32 u) { union { u32 i; float f; } v; v.i = u << 16; return v.f; }
__device__ __forceinline__ float bfhi(u32 u) { union { u32 i; float f; } v; v.i = u & 0xffff0000u; return v.f; }
__device__ __forceinline__ u32 pack2(float a, float b) { return (u32)f2bf(a) | ((u32)f2bf(b) << 16); }

// v_dot2_f32_bf16 with a channel-selector: acc += bf16(lo or hi of hv).
__device__ __forceinline__ void dot2acc(float& acc, u32 hv, u32 sel) {
    asm("v_dot2_f32_bf16 %0, %1, %2, %0" : "+v"(acc) : "v"(hv), "v"(sel));
}

__device__ __forceinline__ float loadx(const void* p, size_t i, int flag_bf16) {
    return flag_bf16 ? bf2f(((const u16*)p)[i]) : ((const float*)p)[i];
}
__device__ __forceinline__ void storex(void* p, size_t i, float v, int flag_bf16) {
    if (flag_bf16) ((u16*)p)[i] = f2bf(v);
    else           ((float*)p)[i] = v;
}

__device__ __forceinline__ bf16x8 load_afrag_ext(const void* A, size_t off, int flag) {
    if (flag) return *reinterpret_cast<const bf16x8*>((const u16*)A + off);
    const float* f = (const float*)A + off;
    float4 a = *reinterpret_cast<const float4*>(f);
    float4 b = *reinterpret_cast<const float4*>(f + 4);
    bf16x8 r;
    r[0] = (__bf16)a.x; r[1] = (__bf16)a.y; r[2] = (__bf16)a.z; r[3] = (__bf16)a.w;
    r[4] = (__bf16)b.x; r[5] = (__bf16)b.y; r[6] = (__bf16)b.z; r[7] = (__bf16)b.w;
    return r;
}

// ---------------- dtype detection ----------------
__global__ void k_detect(const u32* __restrict__ x, int* __restrict__ flag) {
    int lane = threadIdx.x;
    u32 u = x[lane];
    int e = (u >> 7) & 0xFF;
    int hit = (e >= 100 && e <= 145) ? 1 : 0;
    unsigned long long b = __ballot(hit);
    if (lane == 0) flag[0] = (__popcll(b) >= 32) ? 1 : 0;
}

// ---------------- weight conversion ----------------
struct ConvJob { const void* src; float* dst; int n; };
struct ConvJobs { ConvJob j[12]; };

__global__ void k_wconv(ConvJobs jobs, const int* __restrict__ flagp) {
    const int f = *flagp;
    const int stride = gridDim.x * blockDim.x;
    for (int s = 0; s < 12; ++s) {
        const ConvJob jb = jobs.j[s];
        for (int i = blockIdx.x * blockDim.x + threadIdx.x; i < jb.n; i += stride)
            jb.dst[i] = loadx(jb.src, i, f);
    }
}

struct TJob { const float* W; u16* WT; int K, NC; };
struct TJobs { TJob j[5]; };

__global__ void k_wtrans(TJobs jobs) {
    const int stride = gridDim.x * blockDim.x;
    for (int s = 0; s < 5; ++s) {
        const TJob jb = jobs.j[s];
        const int tot = jb.K * jb.NC;
        for (int i = blockIdx.x * blockDim.x + threadIdx.x; i < tot; i += stride) {
            int k = i / jb.NC, n = i - k * jb.NC;
            jb.WT[n * jb.K + k] = f2bf(jb.W[i]);
        }
    }
}

// ---------------- graph preprocessing: block-chunk radix binning ----------------
static const int CAPSH = 12;        // 4096 entries per (g,bucket) cell (avg fill ~2045)
static const int OVCAP = 65536;     // overflow list capacity (never hit for uniform input)

__global__ __launch_bounds__(256) void k_bin(const int* __restrict__ ei0, const int* __restrict__ ei1,
                                             int* __restrict__ cur, u32* __restrict__ stage,
                                             int2* __restrict__ ov, int* __restrict__ ocnt,
                                             int E, int NB, int nblk) {
    const int g = blockIdx.y;
    const int* ei = g ? ei1 : ei0;
    const int chunk = (E + nblk - 1) / nblk;
    const int e0 = blockIdx.x * chunk;
    const int e1 = (e0 + chunk < E) ? e0 + chunk : E;
    const int tid = threadIdx.x;
    __shared__ int h[512];
    __shared__ int lb[512];
    for (int i = tid; i < NB; i += 256) h[i] = 0;
    __syncthreads();
    for (int e = e0 + tid; e < e1; e += 256) {
        int d = __builtin_nontemporal_load(ei + E + e);
        atomicAdd(&h[d >> 7], 1);
    }
    __syncthreads();
    for (int b = tid; b < NB; b += 256) {
        int c = h[b];
        lb[b] = c ? atomicAdd(&cur[g * NB + b], c) : 0;
    }
    __syncthreads();
    for (int i = tid; i < NB; i += 256) h[i] = 0;
    __syncthreads();
    for (int e = e0 + tid; e < e1; e += 256) {
        int s = __builtin_nontemporal_load(ei + e);
        int d = ei[E + e];  // re-read: L2-resident from pass 1
        int b = d >> 7;
        int p = lb[b] + atomicAdd(&h[b], 1);
        if (p < (1 << CAPSH)) {
            stage[((size_t)(g * NB + b) << CAPSH) + p] = (u32)s | ((u32)(d & 127) << 16);
        } else {
            int oi = atomicAdd(ocnt, 1);
            if (oi < OVCAP) ov[oi] = make_int2(s, d | (g << 24));
        }
    }
}

__global__ __launch_bounds__(256) void k_bscan(const int* __restrict__ cur, const int2* __restrict__ ov,
                                               const int* __restrict__ ocnt, int* __restrict__ bbase,
                                               int* __restrict__ rowptr, int N, int E, int NB) {
    __shared__ int tot[2][512];
    const int tid = threadIdx.x;
    for (int g = 0; g < 2; ++g)
        for (int i = tid; i < 512; i += 256) {
            int s = 0;
            if (i < NB) {
                int cv = cur[g * NB + i];
                s = (cv < (1 << CAPSH)) ? cv : (1 << CAPSH);
            }
            tot[g][i] = s;
        }
    __syncthreads();
    int no = *ocnt; if (no > OVCAP) no = OVCAP;
    for (int i = tid; i < no; i += 256) {
        int y = ov[i].y;
        atomicAdd(&tot[y >> 24][(y & 0xFFFFFF) >> 7], 1);
    }
    __syncthreads();
    int o00 = tot[0][tid], o01 = tot[0][tid + 256];
    int o10 = tot[1][tid], o11 = tot[1][tid + 256];
    for (int off = 1; off < 512; off <<= 1) {
        int a0 = tot[0][tid]       + ((tid >= off)       ? tot[0][tid - off]       : 0);
        int a1 = tot[0][tid + 256] + ((tid + 256 >= off) ? tot[0][tid + 256 - off] : 0);
        int b0 = tot[1][tid]       + ((tid >= off)       ? tot[1][tid - off]       : 0);
        int b1 = tot[1][tid + 256] + ((tid + 256 >= off) ? tot[1][tid + 256 - off] : 0);
        __syncthreads();
        tot[0][tid] = a0; tot[0][tid + 256] = a1;
        tot[1][tid] = b0; tot[1][tid + 256] = b1;
        __syncthreads();
    }
    if (tid < NB)       { bbase[tid]            = tot[0][tid] - o00;       bbase[NB + tid]       = tot[1][tid] - o10; }
    if (tid + 256 < NB) { bbase[tid + 256]      = tot[0][tid + 256] - o01; bbase[NB + tid + 256] = tot[1][tid + 256] - o11; }
    if (tid == 0) {
        rowptr[N] = E;
        rowptr[(size_t)(N + 1) + N] = E;
    }
}

__global__ __launch_bounds__(256) void k_scatter(const int* __restrict__ cur, const u32* __restrict__ stage,
                                                 const int2* __restrict__ ov, const int* __restrict__ ocnt,
                                                 const int* __restrict__ bbase, int* __restrict__ rowptr,
                                                 float* __restrict__ dinv, int* __restrict__ csr,
                                                 int N, int E, int NB) {
    const int g = blockIdx.y, b = blockIdx.x, tid = threadIdx.x;
    const int lo = b << 7;
    int R = N - lo; if (R > 128) R = 128;
    __shared__ int hist[128], scn[128], curs[128];
    if (tid < 128) hist[tid] = 0;
    __syncthreads();
    int cv = cur[g * NB + b];
    const int n = (cv < (1 << CAPSH)) ? cv : (1 << CAPSH);
    const u32* sp = stage + ((size_t)(g * NB + b) << CAPSH);
    for (int i = tid; i < n; i += 256) atomicAdd(&hist[sp[i] >> 16], 1);
    int no = *ocnt; if (no > OVCAP) no = OVCAP;
    for (int i = tid; i < no; i += 256) {
        int y = ov[i].y;
        if ((y >> 24) != g) continue;
        int d = y & 0xFFFFFF;
        if (d >= lo && d < lo + 128) atomicAdd(&hist[d - lo], 1);
    }
    __syncthreads();
    int orig = (tid < 128) ? hist[tid] : 0;
    if (tid < 128) scn[tid] = orig;
    __syncthreads();
    for (int off = 1; off < 128; off <<= 1) {
        int v = 0;
        if (tid < 128) v = scn[tid] + ((tid >= off) ? scn[tid - off] : 0);
        __syncthreads();
        if (tid < 128) scn[tid] = v;
        __syncthreads();
    }
    const int base = bbase[g * NB + b];
    if (tid < R) {
        int ex = base + scn[tid] - orig;   // exclusive prefix
        rowptr[(size_t)g * (N + 1) + lo + tid] = ex;
        curs[tid] = ex;
        dinv[(size_t)g * N + lo + tid] = rsqrtf((float)(orig + 1));  // +1 self loop
    }
    __syncthreads();
    int* out = csr + (size_t)g * E;
    for (int i = tid; i < n; i += 256) {
        u32 v = sp[i];
        int pos = atomicAdd(&curs[v >> 16], 1);
        out[pos] = (int)(v & 0xFFFFu);
    }
    for (int i = tid; i < no; i += 256) {
        int y = ov[i].y;
        if ((y >> 24) != g) continue;
        int d = y & 0xFFFFFF;
        if (d >= lo && d < lo + 128) {
            int pos = atomicAdd(&curs[d - lo], 1);
            out[pos] = ov[i].x;
        }
    }
}

// ---------------- MFMA GEMM ----------------
template <int K, int NC, bool AEXT, bool BIAS, bool RELU, bool NORM, bool OEXT, bool SCALE, int ARS>
__global__ __launch_bounds__(256) void k_mgemm(const void* __restrict__ A0, const void* __restrict__ A1,
                                               size_t astride, const u16* __restrict__ WT,
                                               const float* __restrict__ bias, void* __restrict__ outv,
                                               size_t out_off, size_t ostride, int M,
                                               const int* __restrict__ flagp,
                                               const float* __restrict__ dvp) {
    constexpr int NT = NC / 16;
    constexpr int KI = K / 32;
    constexpr int RS = (ARS == 0) ? K : ARS;
    const int flag = *flagp;
    const int g = blockIdx.y;
    const void* Av = g ? A1 : A0;
    const int lane = threadIdx.x & 63;
    const int wave = threadIdx.x >> 6;
    const int q = lane >> 4;
    const int c = lane & 15;
    const int m0 = blockIdx.x * 64 + wave * 16;
    int arow = m0 + c;
    if (arow > M - 1) arow = M - 1;
    const size_t abase = (size_t)g * astride + (size_t)arow * RS;

    bf16x8 afr[KI];
#pragma unroll
    for (int ki = 0; ki < KI; ++ki) {
        size_t off = abase + (size_t)ki * 32 + q * 8;
        if (AEXT) afr[ki] = load_afrag_ext(Av, off, flag);
        else      afr[ki] = *reinterpret_cast<const bf16x8*>((const u16*)Av + off);
    }

    f32x4 acc[NT];
#pragma unroll
    for (int t = 0; t < NT; ++t) acc[t] = (f32x4){0.f, 0.f, 0.f, 0.f};

#pragma unroll
    for (int ki = 0; ki < KI; ++ki) {
#pragma unroll
        for (int t = 0; t < NT; ++t) {
            const u16* bptr = WT + (size_t)(t * 16 + c) * K + ki * 32 + q * 8;
            bf16x8 bfr = *reinterpret_cast<const bf16x8*>(bptr);
            acc[t] = __builtin_amdgcn_mfma_f32_16x16x32_bf16(afr[ki], bfr, acc[t], 0, 0, 0);
        }
    }

#pragma unroll
    for (int t = 0; t < NT; ++t) {
        float bv = BIAS ? bias[t * 16 + c] : 0.f;
#pragma unroll
        for (int r = 0; r < 4; ++r) {
            float v = acc[t][r] + bv;
            if (RELU) v = fmaxf(v, 0.f);
            acc[t][r] = v;
        }
    }

    if constexpr (NORM) {
        float ss[4] = {0.f, 0.f, 0.f, 0.f};
#pragma unroll
        for (int t = 0; t < NT; ++t)
#pragma unroll
            for (int r = 0; r < 4; ++r) ss[r] += acc[t][r] * acc[t][r];
#pragma unroll
        for (int r = 0; r < 4; ++r) {
#pragma unroll
            for (int m = 1; m < 16; m <<= 1) ss[r] += __shfl_xor(ss[r], m, 64);
            float s = 1.f / fmaxf(sqrtf(ss[r]), 1e-12f);
#pragma unroll
            for (int t = 0; t < NT; ++t) acc[t][r] *= s;
        }
    }

    const size_t obase = out_off + (size_t)g * ostride;
#pragma unroll
    for (int r = 0; r < 4; ++r) {
        const int grow = m0 + q * 4 + r;
        if (grow < M) {
            float sc = 1.f;
            if constexpr (SCALE) sc = dvp[(size_t)g * M + grow];
#pragma unroll
            for (int t = 0; t < NT; ++t) {
                float v = SCALE ? acc[t][r] * sc : acc[t][r];
                size_t oi = obase + (size_t)grow * NC + t * 16 + c;
                if (OEXT) storex(outv, oi, v, flag);
                else      ((u16*)outv)[oi] = f2bf(v);
            }
        }
    }
}

// ---------------- fused GCN layer-1 aggregation + layer-2 transform ----------------
// role = bid&7 -> XCD: g = role>>2, quarter = role&3. Block = 16 nodes
// (4 per wave). Per node: gather-reduce (identical inner loop to the 57us
// k_agg128), epilogue relu(dn*sum+b1) -> Qb row staged in a 4KB XOR-swizzled
// LDS tile (never touches HBM). After a barrier, each wave computes one
// 16-col tile of H2 = (Qb @ W2) * dinv via 4x mfma_16x16x32 (A-frag from LDS,
// fragment pattern mirrors k_mgemm). Saves the 25.6MB Qb write + 25.6MB
// read + the mgemm2 dispatch.
__global__ __launch_bounds__(256) void k_agg128f(const u32* __restrict__ H, const int* __restrict__ rowptr,
                                                 const int* __restrict__ csr, const float* __restrict__ dinv,
                                                 const float* __restrict__ bias, const u16* __restrict__ W2T,
                                                 u16* __restrict__ H2, int N, int E, int Q) {
    const u32 SL = 0x00003f80u, SH = 0x3f800000u;   // bf16 1.0 selectors
    const int bid = blockIdx.x;
    const int role = bid & 7;
    const int g = role >> 2;
    const int sub = role & 3;
    const int blk16 = bid >> 3;
    const int lane = threadIdx.x & 63;
    const int wv = threadIdx.x >> 6;
    const int half = lane >> 5;
    const int w = lane & 31;
    const u32* h2 = H + (size_t)g * N * 64 + 2 * w;
    const int* rp = rowptr + (size_t)g * (N + 1);
    const int* cs = csr + (size_t)g * E;

    __shared__ __align__(16) u32 qlds[16][64];   // 16 Qb rows, XOR-swizzled

#pragma unroll
    for (int i = 0; i < 4; ++i) {
        const int tr = wv * 4 + i;
        const int nl = blk16 * 16 + tr;
        const bool valid = (nl < Q) && (sub * Q + nl < N);
        const int node = valid ? sub * Q + nl : 0;
        const float dn = dinv[(size_t)g * N + node];
        int e = rp[node];
        const int end = rp[node + 1];
        float a0 = 0.f, a1 = 0.f, a2 = 0.f, a3 = 0.f;
        if (half == 0) {
            uint2 sv = *reinterpret_cast<const uint2*>(h2 + (size_t)node * 64);
            dot2acc(a0, sv.x, SL); dot2acc(a1, sv.x, SH);
            dot2acc(a2, sv.y, SL); dot2acc(a3, sv.y, SH);
        }
        while (e < end) {
            int cnt = end - e; if (cnt > 64) cnt = 64;
            int my = (lane < cnt) ? cs[e + lane] : 0;
            int j = 0;
            for (; j + 8 <= cnt; j += 8) {
                int s0 = __shfl(my, j + half, 64);
                int s1 = __shfl(my, j + 2 + half, 64);
                int s2 = __shfl(my, j + 4 + half, 64);
                int s3 = __shfl(my, j + 6 + half, 64);
                uint2 h0 = *reinterpret_cast<const uint2*>(h2 + (size_t)s0 * 64);
                uint2 h1 = *reinterpret_cast<const uint2*>(h2 + (size_t)s1 * 64);
                uint2 hh2 = *reinterpret_cast<const uint2*>(h2 + (size_t)s2 * 64);
                uint2 h3 = *reinterpret_cast<const uint2*>(h2 + (size_t)s3 * 64);
                dot2acc(a0, h0.x, SL); dot2acc(a1, h0.x, SH); dot2acc(a2, h0.y, SL); dot2acc(a3, h0.y, SH);
                dot2acc(a0, h1.x, SL); dot2acc(a1, h1.x, SH); dot2acc(a2, h1.y, SL); dot2acc(a3, h1.y, SH);
                dot2acc(a0, hh2.x, SL); dot2acc(a1, hh2.x, SH); dot2acc(a2, hh2.y, SL); dot2acc(a3, hh2.y, SH);
                dot2acc(a0, h3.x, SL); dot2acc(a1, h3.x, SH); dot2acc(a2, h3.y, SL); dot2acc(a3, h3.y, SH);
            }
            for (; j < cnt; j += 2) {
                int idx = j + half;
                int src = __shfl(my, idx < cnt ? idx : 0, 64);
                if (idx < cnt) {
                    uint2 hv = *reinterpret_cast<const uint2*>(h2 + (size_t)src * 64);
                    dot2acc(a0, hv.x, SL); dot2acc(a1, hv.x, SH);
                    dot2acc(a2, hv.y, SL); dot2acc(a3, hv.y, SH);
                }
            }
            e += cnt;
        }
        a0 += __shfl_xor(a0, 32, 64);
        a1 += __shfl_xor(a1, 32, 64);
        a2 += __shfl_xor(a2, 32, 64);
        a3 += __shfl_xor(a3, 32, 64);
        float x = half ? a2 : a0;
        float y = half ? a3 : a1;
        const int c0 = 4 * w + 2 * half;
        float r0 = fmaxf(x * dn + bias[c0], 0.f);
        float r1 = fmaxf(y * dn + bias[c0 + 1], 0.f);
        const int jc = 2 * w + half;
        qlds[tr][jc ^ ((tr & 7) << 2)] = pack2(r0, r1);
    }
    __syncthreads();

    // block GEMM: H2[16 nodes][64] = qlds[16][128bf16] @ W2T, scaled by dinv
    const int q = lane >> 4;
    const int c = lane & 15;
    f32x4 acc = (f32x4){0.f, 0.f, 0.f, 0.f};
#pragma unroll
    for (int ki = 0; ki < 4; ++ki) {
        const int base = (ki * 16 + q * 4) ^ ((c & 7) << 2);
        bf16x8 afr = *reinterpret_cast<const bf16x8*>(&qlds[c][base]);
        const u16* bptr = W2T + (size_t)(wv * 16 + c) * 128 + ki * 32 + q * 8;
        bf16x8 bfr = *reinterpret_cast<const bf16x8*>(bptr);
        acc = __builtin_amdgcn_mfma_f32_16x16x32_bf16(afr, bfr, acc, 0, 0, 0);
    }
#pragma unroll
    for (int r = 0; r < 4; ++r) {
        const int tr = q * 4 + r;
        const int nl = blk16 * 16 + tr;
        if (nl < Q) {
            const int node = sub * Q + nl;
            if (node < N) {
                float sc = dinv[(size_t)g * N + node];
                H2[(size_t)(g * N + node) * 64 + wv * 16 + c] = f2bf(acc[r] * sc);
            }
        }
    }
}

// ---------------- layer-2 aggregation (unchanged structure) ----------------
__global__ __launch_bounds__(256) void k_agg64(const u32* __restrict__ H, const int* __restrict__ rowptr,
                                               const int* __restrict__ csr, const float* __restrict__ dinv,
                                               const float* __restrict__ bias, u32* __restrict__ out,
                                               int N, int E, int Q) {
    const u32 SL = 0x00003f80u, SH = 0x3f800000u;
    const int bid = blockIdx.x;
    const int role = bid & 7;
    const int g = role >> 2;
    const int sub = role & 3;
    const int nl = (bid >> 3) * 4 + (threadIdx.x >> 6);
    if (nl >= Q) return;
    const int node = sub * Q + nl;
    if (node >= N) return;
    const int lane = threadIdx.x & 63;
    const int quad = lane >> 4;
    const int w = lane & 15;
    const u32* h2 = H + (size_t)g * N * 32 + 2 * w;
    const int* rp = rowptr + (size_t)g * (N + 1);
    const int* cs = csr + (size_t)g * E;
    const float dn = dinv[(size_t)g * N + node];
    int e = rp[node];
    const int end = rp[node + 1];
    float a0 = 0.f, a1 = 0.f, a2 = 0.f, a3 = 0.f;
    if (quad == 0) {
        uint2 sv = *reinterpret_cast<const uint2*>(h2 + (size_t)node * 32);
        dot2acc(a0, sv.x, SL); dot2acc(a1, sv.x, SH);
        dot2acc(a2, sv.y, SL); dot2acc(a3, sv.y, SH);
    }
    while (e < end) {
        int cnt = end - e; if (cnt > 64) cnt = 64;
        int my = (lane < cnt) ? cs[e + lane] : 0;
        int j = 0;
        for (; j + 16 <= cnt; j += 16) {
            int s0 = __shfl(my, j + quad, 64);
            int s1 = __shfl(my, j + 4 + quad, 64);
            int s2 = __shfl(my, j + 8 + quad, 64);
            int s3 = __shfl(my, j + 12 + quad, 64);
            uint2 h0 = *reinterpret_cast<const uint2*>(h2 + (size_t)s0 * 32);
            uint2 h1 = *reinterpret_cast<const uint2*>(h2 + (size_t)s1 * 32);
            uint2 hh2 = *reinterpret_cast<const uint2*>(h2 + (size_t)s2 * 32);
            uint2 h3 = *reinterpret_cast<const uint2*>(h2 + (size_t)s3 * 32);
            dot2acc(a0, h0.x, SL); dot2acc(a1, h0.x, SH); dot2acc(a2, h0.y, SL); dot2acc(a3, h0.y, SH);
            dot2acc(a0, h1.x, SL); dot2acc(a1, h1.x, SH); dot2acc(a2, h1.y, SL); dot2acc(a3, h1.y, SH);
            dot2acc(a0, hh2.x, SL); dot2acc(a1, hh2.x, SH); dot2acc(a2, hh2.y, SL); dot2acc(a3, hh2.y, SH);
            dot2acc(a0, h3.x, SL); dot2acc(a1, h3.x, SH); dot2acc(a2, h3.y, SL); dot2acc(a3, h3.y, SH);
        }
        for (; j < cnt; j += 4) {
            int idx = j + quad;
            int src = __shfl(my, idx < cnt ? idx : 0, 64);
            if (idx < cnt) {
                uint2 hv = *reinterpret_cast<const uint2*>(h2 + (size_t)src * 32);
                dot2acc(a0, hv.x, SL); dot2acc(a1, hv.x, SH);
                dot2acc(a2, hv.y, SL); dot2acc(a3, hv.y, SH);
            }
        }
        e += cnt;
    }
    a0 += __shfl_xor(a0, 16, 64); a0 += __shfl_xor(a0, 32, 64);
    a1 += __shfl_xor(a1, 16, 64); a1 += __shfl_xor(a1, 32, 64);
    a2 += __shfl_xor(a2, 16, 64); a2 += __shfl_xor(a2, 32, 64);
    a3 += __shfl_xor(a3, 16, 64); a3 += __shfl_xor(a3, 32, 64);
    if (quad < 2) {
        float x = quad ? a2 : a0;
        float y = quad ? a3 : a1;
        const int c0 = 4 * w + 2 * quad;
        float r0 = fmaxf(x * dn + bias[c0], 0.f);
        float r1 = fmaxf(y * dn + bias[c0 + 1], 0.f);
        out[((size_t)g * N + node) * 32 + 2 * w + quad] = pack2(r0, r1);
    }
}

// ---------------- cluster head ----------------
__global__ __launch_bounds__(256) void k_clus(const u16* __restrict__ v, const float* __restrict__ Wc2,
                                              const float* __restrict__ bc2, void* __restrict__ outv,
                                              size_t out_off, size_t ostride, int N,
                                              const int* __restrict__ flagp) {
    const int g = blockIdx.y;
    const int node = blockIdx.x * 4 + (threadIdx.x >> 6);
    if (node >= N) return;
    const int flag = *flagp;
    const int lane = threadIdx.x & 63;
    float ul = bf2f(v[((size_t)g * N + node) * 128 + 64 + lane]);
    float a0 = ul * Wc2[lane * 3 + 0];
    float a1 = ul * Wc2[lane * 3 + 1];
    float a2 = ul * Wc2[lane * 3 + 2];
#pragma unroll
    for (int m = 1; m < 64; m <<= 1) {
        a0 += __shfl_xor(a0, m, 64);
        a1 += __shfl_xor(a1, m, 64);
        a2 += __shfl_xor(a2, m, 64);
    }
    a0 += bc2[0]; a1 += bc2[1]; a2 += bc2[2];
    float mx = fmaxf(a0, fmaxf(a1, a2));
    float e0 = expf(a0 - mx), e1 = expf(a1 - mx), e2 = expf(a2 - mx);
    float inv = 1.f / (e0 + e1 + e2);
    if (lane < 3) {
        float r = (lane == 0) ? e0 : ((lane == 1) ? e1 : e2);
        storex(outv, out_off + (size_t)g * ostride + (size_t)node * 3 + lane, r * inv, flag);
    }
}

// ---------------- launcher ----------------
extern "C" void kernel_launch(void* const* d_in, const int* in_sizes, int n_in,
                              void* d_out, int out_size, void* d_ws, size_t ws_size,
                              hipStream_t stream) {
    const int N = in_sizes[0] / 128;   // 50000
    const int E = in_sizes[1] / 2;     // 800000
    const int* ei0 = (const int*)d_in[1];
    const int* ei1 = (const int*)d_in[3];
    const int NB = (N + 127) >> 7;     // 391 buckets of 128 nodes

    size_t off = 0;
    auto alloc = [&](size_t bytes) -> void* {
        void* p = (char*)d_ws + off;
        off += (bytes + 255) & ~(size_t)255;
        return p;
    };
    int* flag = (int*)alloc(256);
    const int wcnt[12] = {128 * 128, 128, 128 * 64, 64, 64 * 64, 64, 64 * 128, 128, 64 * 64, 64, 64 * 3, 3};
    float* wf[12];
    for (int i = 0; i < 12; ++i) {
        if (i == 5) { wf[5] = (float*)alloc(128 * 4); continue; }   // fused [bp1;bc1]
        if (i == 9) { wf[9] = wf[5] + 64; continue; }
        wf[i] = (float*)alloc((size_t)wcnt[i] * 4);
    }
    float* b1f = wf[1]; float* b2f = wf[3]; float* bpcf = wf[5]; float* bp2f = wf[7];
    float* Wc2f = wf[10]; float* bc2f = wf[11];
    u16* W1T  = (u16*)alloc(128 * 128 * 2);
    u16* W2T  = (u16*)alloc(64 * 128 * 2);
    u16* Wp1T = (u16*)alloc(64 * 64 * 2);   // adjacent to Wc1T: fused [128][64]
    u16* Wc1T = (u16*)alloc(64 * 64 * 2);
    u16* Wp2T = (u16*)alloc(128 * 64 * 2);
    u16* WpcT = Wp1T;                       // fused head-1 weights

    const int ncell = 2 * NB;
    int* cur    = (int*)alloc((size_t)(ncell + 1) * 4);   // +1: overflow count
    int* ocnt   = cur + ncell;
    int2* ov    = (int2*)alloc((size_t)OVCAP * 8);
    u32* stage  = (u32*)alloc(((size_t)ncell << CAPSH) * 4);
    int* bbase  = (int*)alloc((size_t)2 * NB * 4);
    int* rowptr = (int*)alloc((size_t)2 * (N + 1) * 4);
    float* dinv = (float*)alloc((size_t)2 * N * 4);
    int* csr    = (int*)alloc((size_t)2 * E * 4);
    u16* A1 = (u16*)alloc((size_t)2 * N * 128 * 2);   // layer-1 H (gather source)
    u16* Qb = (u16*)alloc((size_t)2 * N * 128 * 2);   // H2 (first half) then U2
    u16* H2 = Qb;                                      // layer-2 H [2][N][64]
    u16* U2 = Qb;                                      // fused head-1 out [2][N][128]
    u16* Z  = (u16*)alloc((size_t)2 * N * 64 * 2);
    (void)ws_size; (void)n_in; (void)out_size;

    k_detect<<<1, 64, 0, stream>>>((const u32*)d_in[0], flag);
    ConvJobs jobs;
    for (int i = 0; i < 12; ++i) jobs.j[i] = ConvJob{d_in[4 + i], wf[i], wcnt[i]};
    k_wconv<<<64, 256, 0, stream>>>(jobs, flag);
    TJobs tj;
    tj.j[0] = TJob{wf[0], W1T, 128, 128};
    tj.j[1] = TJob{wf[2], W2T, 128, 64};
    tj.j[2] = TJob{wf[4], Wp1T, 64, 64};
    tj.j[3] = TJob{wf[8], Wc1T, 64, 64};
    tj.j[4] = TJob{wf[6], Wp2T, 64, 128};
    k_wtrans<<<40, 256, 0, stream>>>(tj);

    hipMemsetAsync(cur, 0, (size_t)(ncell + 1) * 4, stream);
    const int NBLK = 128;   // per-graph blocks: chunk ~6250 edges -> runs of ~16 (1 line)
    k_bin<<<dim3(NBLK, 2), 256, 0, stream>>>(ei0, ei1, cur, stage, ov, ocnt, E, NB, NBLK);
    k_bscan<<<1, 256, 0, stream>>>(cur, ov, ocnt, bbase, rowptr, N, E, NB);
    k_scatter<<<dim3(NB, 2), 256, 0, stream>>>(cur, stage, ov, ocnt, bbase, rowptr, dinv, csr, N, E, NB);

    const dim3 gM((N + 63) / 64, 2);
    const dim3 gA((N + 3) / 4, 2);
    const int Q = (N + 3) / 4;               // nodes per quarter-role
    const dim3 gAgg(8 * ((Q + 3) / 4));      // agg64 roles
    const dim3 gAgg16(8 * ((Q + 15) / 16));  // fused agg128+gemm2 roles (16 nodes/block)

    // layer 1 (output pre-scaled by dinv[row])
    k_mgemm<128, 128, true, false, false, false, false, true, 0><<<gM, 256, 0, stream>>>(
        d_in[0], d_in[2], 0, W1T, nullptr, A1, 0, (size_t)N * 128, N, flag, dinv);
    // fused: layer-1 aggregation + layer-2 GEMM (H2 pre-scaled by dinv[row])
    k_agg128f<<<gAgg16, 256, 0, stream>>>((const u32*)A1, rowptr, csr, dinv, b1f, W2T, H2, N, E, Q);
    k_agg64<<<gAgg, 256, 0, stream>>>((const u32*)H2, rowptr, csr, dinv, b2f, (u32*)Z, N, E, Q);

    // fused head-1: [Wp1 | Wc1] -> U2[N][128] (cols 0-63 inst, 64-127 clus)
    k_mgemm<64, 128, false, true, true, false, false, false, 0><<<gM, 256, 0, stream>>>(
        Z, Z, (size_t)N * 64, WpcT, bpcf, U2, 0, (size_t)N * 128, N, flag, nullptr);
    // instance head-2: reads U2 cols 0-63 (row stride 128)
    k_mgemm<64, 128, false, true, false, true, true, false, 128><<<gM, 256, 0, stream>>>(
        U2, U2, (size_t)N * 128, Wp2T, bp2f, d_out, 0, (size_t)N * 128, N, flag, nullptr);
    // cluster head: reads U2 cols 64-127
    k_clus<<<gA, 256, 0, stream>>>(U2, Wc2f, bc2f, d_out,
                                   (size_t)2 * N * 128, (size_t)N * 3, N, flag);
}